// Round 11
// baseline (370.967 us; speedup 1.0000x reference)
//
#include <hip/hip_runtime.h>
#include <stdint.h>

#define CONF_T 0.01f
#define NMS_T  0.45f
#define M_TOP  200
#define SM_ROWS 64    // rows per softmax block (64 threads); LDS 20.7 KB -> 7 blocks/CU
#define TK_BS  256    // topk block size
#define TCAP   4096   // topk bracket buffer capacity (LDS)

__device__ __forceinline__ uint32_t fkey(float f) {
    uint32_t u = __float_as_uint(f);
    return (u & 0x80000000u) ? ~u : (u | 0x80000000u);
}
__device__ __forceinline__ float fkey_inv(uint32_t k) {
    uint32_t u = (k & 0x80000000u) ? (k & 0x7FFFFFFFu) : ~k;
    return __uint_as_float(u);
}

// Parallel suffix-scan bin selection over nb bins (nb multiple of 256).
// Wave-level suffix scan via shfl_down doubling + 4-entry cross-wave combine:
// 2 barriers per call (was ~19 with the LDS ladder).
__device__ __forceinline__ void suffix_select(
        uint32_t* hist, uint32_t* wsum, int nb, uint32_t pref, int shift,
        uint32_t wantv, uint32_t* s_prefix, uint32_t* s_want) {
    int tid = threadIdx.x;
    int lane = tid & 63, w = tid >> 6;
    int bpt = nb >> 8;
    int base = tid * bpt;
    uint32_t loc = 0;
    for (int j = 0; j < bpt; j++) loc += hist[base + j];
    uint32_t sfx = loc;                       // inclusive suffix within wave
    #pragma unroll
    for (int d = 1; d < 64; d <<= 1) {
        uint32_t y = __shfl_down(sfx, d);
        if (lane + d < 64) sfx += y;
    }
    if (lane == 0) wsum[w] = sfx;             // wave total
    __syncthreads();
    uint32_t later = 0;
    for (int j = w + 1; j < TK_BS / 64; j++) later += wsum[j];
    uint32_t run = (sfx - loc) + later;       // suffix strictly after my chunk
    for (int j = bpt - 1; j >= 0; j--) {
        uint32_t h = hist[base + j];
        uint32_t s2 = run + h;
        if (run < wantv && s2 >= wantv) {     // exactly one (thread,j) hits
            *s_prefix = pref | ((uint32_t)(base + j) << shift);
            *s_want   = wantv - run;
        }
        run = s2;
    }
    __syncthreads();
}

__device__ __forceinline__ float4 decode_box(float4 l, float4 d) {
    float cx = d.x + (l.x * 0.1f) * d.z;
    float cy = d.y + (l.y * 0.1f) * d.w;
    float w  = d.z * expf(l.z * 0.2f);
    float h  = d.w * expf(l.w * 0.2f);
    float x1 = cx - w * 0.5f, y1 = cy - h * 0.5f;
    float x2 = x1 + w, y2 = y1 + h;
    float4 o;
    o.x = fminf(fmaxf(x1, 0.f), 1.f);
    o.y = fminf(fmaxf(y1, 0.f), 1.f);
    o.z = fminf(fmaxf(x2, 0.f), 1.f);
    o.w = fminf(fmaxf(y2, 0.f), 1.f);
    return o;
}

// ---------------- Kernel B: softmax + transpose (R8-proven form) ----------------
__global__ __launch_bounds__(SM_ROWS) void softmax_kernel(
        const float* __restrict__ conf, float* __restrict__ sc,
        int B, int N, int C) {
    __shared__ float rows[SM_ROWS * 81];
    int tid = threadIdx.x;
    int BN = B * N;
    long long r0 = (long long)blockIdx.x * SM_ROWS;
    int nrows = BN - (int)r0; if (nrows > SM_ROWS) nrows = SM_ROWS;
    int totalf = nrows * 81;
    const float* g = conf + r0 * 81;
    int total4 = totalf >> 2;
    const float4* g4 = (const float4*)g;
    float4* l4 = (float4*)rows;
    for (int i = tid; i < total4; i += SM_ROWS) l4[i] = g4[i];
    for (int i = (total4 << 2) + tid; i < totalf; i += SM_ROWS) rows[i] = g[i];
    __syncthreads();
    if (tid < nrows) {
        float* p = rows + tid * 81;
        float m = p[0];
        for (int c = 1; c < 81; c++) m = fmaxf(m, p[c]);
        float s = 0.f;
        for (int c = 0; c < 81; c++) { float e = expf(p[c] - m); p[c] = e; s += e; }
        int r = (int)r0 + tid;
        int b = r / N, n = r % N;
        size_t base = ((size_t)b * (C - 1)) * N + n;
        for (int c = 1; c < 81; c++) {
            sc[base + (size_t)(c - 1) * N] = p[c] / s;
        }
    }
}

// ---------------- Kernel C: top-200 + inline decode + parallel bitmask NMS ----------
__global__ __launch_bounds__(TK_BS) void topk_kernel(
        const float* __restrict__ sc, const float* __restrict__ loc,
        const float* __restrict__ dbox,
        float* __restrict__ cand,
        float* __restrict__ cmpval, int* __restrict__ cmpidx,
        int* __restrict__ pcnt,
        int B, int N, int Cm1, int M) {
    const uint32_t KEYN1 = 0x407FFFFFu;        // fkey(-1.0f)
    const uint32_t BIN_N1 = KEYN1 >> 21;       // 0x203
    __shared__ __align__(16) uint32_t hist[2048];
    __shared__ __align__(16) uint32_t tk[TCAP];
    __shared__ int      tix[TCAP];
    __shared__ uint32_t wsum[TK_BS / 64];
    __shared__ uint32_t s_prefix, s_want;
    __shared__ uint32_t ngt, ntie, tcnt;
    __shared__ float    e_val[256];
    __shared__ int      e_idx[256];
    __shared__ int      tiebuf[256];
    __shared__ float    s_sc[M_TOP];
    __shared__ float    s_x1[M_TOP], s_y1[M_TOP], s_x2[M_TOP], s_y2[M_TOP], s_ar[M_TOP];
    __shared__ unsigned long long s_keep[4];
    __shared__ int s_base;

    int row = blockIdx.x;                      // b*Cm1 + c
    int b = row / Cm1, c = row % Cm1;
    int tid = threadIdx.x;
    const float* v = sc + (size_t)row * N;
    const float4* v4 = (const float4*)v;
    int n4 = N >> 2;

    // ---- sample phase ----
    bool sampled = (N >= 2048) && ((N & 7) == 0);
    uint32_t lo_key = 0xFFFFFFFFu, hi_key = 0xFFFFFFFFu;
    if (sampled) {
        int stride = N >> 3;
        for (int s = 0; s < 8; s++) {
            float f = v[s * stride + tid];
            tk[s * 256 + tid] = fkey(f > CONF_T ? f : -1.0f);
        }
        for (int i = tid; i < 2048; i += TK_BS) hist[i] = 0;
        __syncthreads();
        for (int i = tid; i < 2048; i += TK_BS) atomicAdd(&hist[tk[i] >> 21], 1u);
        __syncthreads();
        suffix_select(hist, wsum, 2048, 0u, 21, 3u, &s_prefix, &s_want);
        uint32_t h = s_prefix >> 21;
        suffix_select(hist, wsum, 2048, 0u, 21, 25u, &s_prefix, &s_want);
        uint32_t l = s_prefix >> 21;
        hi_key = ((h + 1) << 21) - 1u;
        lo_key = (l << 21) - 1u;
        sampled = (l > BIN_N1);
    }

    e_val[tid] = -1.0f; e_idx[tid] = tid;
    if (tid == 0) { ngt = 0; ntie = 0; tcnt = 0; }
    __syncthreads();

    bool ok = false;
    uint32_t G = 0, T = 0;
    if (sampled) {
        for (int i = tid; i < n4; i += TK_BS) {
            float4 f = v4[i];
            float mv[4] = { f.x > CONF_T ? f.x : -1.0f, f.y > CONF_T ? f.y : -1.0f,
                            f.z > CONF_T ? f.z : -1.0f, f.w > CONF_T ? f.w : -1.0f };
            #pragma unroll
            for (int j = 0; j < 4; j++) {
                uint32_t k = fkey(mv[j]);
                if (k > lo_key) {
                    int idx = 4 * i + j;
                    if (k > hi_key) {
                        uint32_t p = atomicAdd(&ngt, 1u);
                        if (p < 256) { e_val[p] = mv[j]; e_idx[p] = idx; }
                    } else {
                        uint32_t p = atomicAdd(&tcnt, 1u);
                        if (p < TCAP) { tk[p] = k; tix[p] = idx; }
                    }
                }
            }
        }
        for (int i = (n4 << 2) + tid; i < N; i += TK_BS) {
            float f = v[i];
            float mv = f > CONF_T ? f : -1.0f;
            uint32_t k = fkey(mv);
            if (k > lo_key) {
                if (k > hi_key) {
                    uint32_t p = atomicAdd(&ngt, 1u);
                    if (p < 256) { e_val[p] = mv; e_idx[p] = i; }
                } else {
                    uint32_t p = atomicAdd(&tcnt, 1u);
                    if (p < TCAP) { tk[p] = k; tix[p] = i; }
                }
            }
        }
        __syncthreads();
        G = ngt; T = tcnt;
        ok = (G <= (uint32_t)M_TOP) && (T <= (uint32_t)TCAP) &&
             (G + T >= (uint32_t)M_TOP);
    }

    uint32_t kth = KEYN1, rfin = 0;
    if (ok) {
        uint32_t want_t = (uint32_t)M_TOP - G;
        if (want_t > 0) {
            for (int i = tid; i < 2048; i += TK_BS) hist[i] = 0;
            __syncthreads();
            for (int i = tid; i < (int)T; i += TK_BS) atomicAdd(&hist[tk[i] >> 21], 1u);
            __syncthreads();
            suffix_select(hist, wsum, 2048, 0u, 21, want_t, &s_prefix, &s_want);
            uint32_t pre0 = s_prefix, w0 = s_want;
            uint32_t bb0 = pre0 >> 21;
            for (int i = tid; i < 2048; i += TK_BS) hist[i] = 0;
            __syncthreads();
            for (int i = tid; i < (int)T; i += TK_BS)
                if ((tk[i] >> 21) == bb0) atomicAdd(&hist[(tk[i] >> 10) & 2047u], 1u);
            __syncthreads();
            suffix_select(hist, wsum, 2048, pre0, 10, w0, &s_prefix, &s_want);
            uint32_t pre1 = s_prefix, w1 = s_want;
            for (int i = tid; i < 1024; i += TK_BS) hist[i] = 0;
            __syncthreads();
            for (int i = tid; i < (int)T; i += TK_BS)
                if ((tk[i] >> 10) == (pre1 >> 10)) atomicAdd(&hist[tk[i] & 1023u], 1u);
            __syncthreads();
            suffix_select(hist, wsum, 1024, pre1, 0, w1, &s_prefix, &s_want);
            kth = s_prefix; rfin = s_want;
            for (int i = tid; i < (int)T; i += TK_BS) {
                uint32_t k = tk[i];
                if (k > kth) {
                    uint32_t p = atomicAdd(&ngt, 1u);
                    if (p < 256) { e_val[p] = fkey_inv(k); e_idx[p] = tix[i]; }
                } else if (k == kth) {
                    uint32_t p = atomicAdd(&ntie, 1u);
                    if (p < 256) tiebuf[p] = tix[i];
                }
            }
            __syncthreads();
        }
    } else {
        // ---- fallback: exact 2-sweep histogram path ----
        e_val[tid] = -1.0f; e_idx[tid] = tid;
        if (tid == 0) { ngt = 0; ntie = 0; tcnt = 0; }
        for (int i = tid; i < 2048; i += TK_BS) hist[i] = 0;
        __syncthreads();
        for (int i = tid; i < n4; i += TK_BS) {
            float4 f = v4[i];
            atomicAdd(&hist[fkey(f.x > CONF_T ? f.x : -1.0f) >> 21], 1u);
            atomicAdd(&hist[fkey(f.y > CONF_T ? f.y : -1.0f) >> 21], 1u);
            atomicAdd(&hist[fkey(f.z > CONF_T ? f.z : -1.0f) >> 21], 1u);
            atomicAdd(&hist[fkey(f.w > CONF_T ? f.w : -1.0f) >> 21], 1u);
        }
        for (int i = (n4 << 2) + tid; i < N; i += TK_BS)
            atomicAdd(&hist[fkey(v[i] > CONF_T ? v[i] : -1.0f) >> 21], 1u);
        __syncthreads();
        suffix_select(hist, wsum, 2048, 0u, 21, M_TOP, &s_prefix, &s_want);
        uint32_t b0 = s_prefix >> 21;
        uint32_t want1 = s_want;
        bool collect_ties = (b0 != BIN_N1);
        for (int i = tid; i < N; i += TK_BS) {
            float f = v[i];
            float mv = f > CONF_T ? f : -1.0f;
            uint32_t k = fkey(mv);
            uint32_t bin = k >> 21;
            if (bin > b0) {
                uint32_t p = atomicAdd(&ngt, 1u);
                if (p < 256) { e_val[p] = mv; e_idx[p] = i; }
            } else if (bin == b0 && collect_ties) {
                uint32_t p = atomicAdd(&tcnt, 1u);
                if (p < TCAP) { tk[p] = k; tix[p] = i; }
            }
        }
        __syncthreads();
        if (collect_ties && tcnt <= TCAP) {
            int Tl = (int)tcnt;
            for (int i = tid; i < 2048; i += TK_BS) hist[i] = 0;
            __syncthreads();
            for (int i = tid; i < Tl; i += TK_BS) atomicAdd(&hist[(tk[i] >> 10) & 2047u], 1u);
            __syncthreads();
            suffix_select(hist, wsum, 2048, b0 << 21, 10, want1, &s_prefix, &s_want);
            uint32_t pre2 = s_prefix; uint32_t want2 = s_want;
            uint32_t b1 = (pre2 >> 10) & 2047u;
            for (int i = tid; i < 1024; i += TK_BS) hist[i] = 0;
            __syncthreads();
            for (int i = tid; i < Tl; i += TK_BS)
                if (((tk[i] >> 10) & 2047u) == b1) atomicAdd(&hist[tk[i] & 1023u], 1u);
            __syncthreads();
            suffix_select(hist, wsum, 1024, pre2, 0, want2, &s_prefix, &s_want);
            kth = s_prefix; rfin = s_want;
            for (int i = tid; i < Tl; i += TK_BS) {
                uint32_t k = tk[i];
                if (k > kth) {
                    uint32_t p = atomicAdd(&ngt, 1u);
                    if (p < 256) { e_val[p] = fkey_inv(k); e_idx[p] = tix[i]; }
                } else if (k == kth) {
                    uint32_t p = atomicAdd(&ntie, 1u);
                    if (p < 256) tiebuf[p] = tix[i];
                }
            }
            __syncthreads();
        } else if (collect_ties) {
            const int shifts[2] = {10, 0};
            const int nbins_[2] = {2048, 1024};
            if (tid == 0) { s_prefix = b0 << 21; s_want = want1; }
            __syncthreads();
            for (int lev = 0; lev < 2; lev++) {
                int shift = shifts[lev];
                int nb = nbins_[lev];
                uint32_t bmask = (uint32_t)nb - 1u;
                uint32_t pref = s_prefix, wantv = s_want;
                uint32_t pmask = 0xFFFFFFFFu << (shift + ((nb == 2048) ? 11 : 10));
                for (int i = tid; i < nb; i += TK_BS) hist[i] = 0;
                __syncthreads();
                for (int i = tid; i < N; i += TK_BS) {
                    float f = v[i];
                    uint32_t k = fkey(f > CONF_T ? f : -1.0f);
                    if ((k & pmask) == (pref & pmask)) atomicAdd(&hist[(k >> shift) & bmask], 1u);
                }
                __syncthreads();
                suffix_select(hist, wsum, nb, pref, shift, wantv, &s_prefix, &s_want);
            }
            kth = s_prefix; rfin = s_want;
            for (int i = tid; i < N; i += TK_BS) {
                float f = v[i];
                float mv = f > CONF_T ? f : -1.0f;
                uint32_t k = fkey(mv);
                if ((k >> 21) == b0) {
                    if (k > kth) {
                        uint32_t p = atomicAdd(&ngt, 1u);
                        if (p < 256) { e_val[p] = mv; e_idx[p] = i; }
                    } else if (k == kth) {
                        uint32_t p = atomicAdd(&ntie, 1u);
                        if (p < 256) tiebuf[p] = i;
                    }
                }
            }
            __syncthreads();
        }
    }

    // ---- ties, rank order, inline box decode -> LDS + cand ----
    uint32_t gcount = min(ngt, (uint32_t)M_TOP);
    uint32_t nt = min(ntie, 256u);
    if (tid < (int)nt) {
        int mine = tiebuf[tid];
        uint32_t rk = 0;
        for (uint32_t j = 0; j < nt; j++) if (tiebuf[j] < mine) rk++;
        if (rk < rfin) {
            uint32_t slot = gcount + rk;
            if (slot < M_TOP) { e_val[slot] = fkey_inv(kth); e_idx[slot] = mine; }
        }
    }
    __syncthreads();
    if (tid < M_TOP) {
        float mv = e_val[tid]; int mi = e_idx[tid];
        uint32_t mk = fkey(mv);
        uint32_t rk = 0;
        for (int j = 0; j < M_TOP; j++) {
            uint32_t jk = fkey(e_val[j]); int ji = e_idx[j];
            if (jk > mk || (jk == mk && ji < mi)) rk++;
        }
        float4 l = ((const float4*)loc)[(size_t)b * N + mi];
        float4 d = ((const float4*)dbox)[mi];
        float4 bx = decode_box(l, d);
        ((float4*)cand)[(size_t)row * M_TOP + rk] = bx;   // for out_kernel gather
        s_sc[rk] = mv;
        s_x1[rk] = bx.x; s_y1[rk] = bx.y; s_x2[rk] = bx.z; s_y2[rk] = bx.w;
    }
    __syncthreads();

    // ---- parallel bitmask NMS (sup matrix aliased onto dead tk buffer) ----
    unsigned long long* sup = (unsigned long long*)tk;   // 200*4*8 = 6400 B <= 16 KB
    if (tid < M_TOP) s_ar[tid] = (s_x2[tid] - s_x1[tid]) * (s_y2[tid] - s_y1[tid]);
    __syncthreads();
    if (tid < M_TOP) {
        float ix1 = s_x1[tid], iy1 = s_y1[tid], ix2 = s_x2[tid], iy2 = s_y2[tid];
        float iar = s_ar[tid];
        unsigned long long m[4] = {0ull, 0ull, 0ull, 0ull};
        for (int j = 0; j < M_TOP; j++) {
            float xx1 = fmaxf(ix1, s_x1[j]);
            float yy1 = fmaxf(iy1, s_y1[j]);
            float xx2 = fminf(ix2, s_x2[j]);
            float yy2 = fminf(iy2, s_y2[j]);
            float inter = fmaxf(xx2 - xx1, 0.f) * fmaxf(yy2 - yy1, 0.f);
            float uni = (s_ar[j] - inter) + iar;
            float iou = inter / uni;
            if (!(iou <= NMS_T)) m[j >> 6] |= 1ull << (j & 63);  // NaN suppresses
        }
        sup[tid * 4 + 0] = m[0]; sup[tid * 4 + 1] = m[1];
        sup[tid * 4 + 2] = m[2]; sup[tid * 4 + 3] = m[3];
    }
    __syncthreads();
    if (tid < 64) {
        int lane = tid;
        unsigned long long r0[4], r1[4], r2[4], r3[4];
        #pragma unroll
        for (int k = 0; k < 4; k++) {
            r0[k] = sup[lane * 4 + k];
            r1[k] = sup[(64 + lane) * 4 + k];
            r2[k] = sup[(128 + lane) * 4 + k];
            r3[k] = (192 + lane < M_TOP) ? sup[(192 + lane) * 4 + k] : 0ull;
        }
        unsigned long long act[4];
        #pragma unroll
        for (int s = 0; s < 4; s++) {
            int j = s * 64 + lane;
            bool a = (j < M_TOP) && (s_sc[j] > CONF_T);
            act[s] = __ballot(a);              // uniform across lanes
        }
        unsigned long long keep[4] = {0ull, 0ull, 0ull, 0ull};
        for (int i = 0; i < M_TOP; i++) {
            int w = i >> 6, b2 = i & 63;
            if ((act[w] >> b2) & 1ull) {
                keep[w] |= 1ull << b2;
                unsigned long long m0, m1, m2, m3;
                if (w == 0)      { m0 = __shfl(r0[0], b2); m1 = __shfl(r0[1], b2); m2 = __shfl(r0[2], b2); m3 = __shfl(r0[3], b2); }
                else if (w == 1) { m0 = __shfl(r1[0], b2); m1 = __shfl(r1[1], b2); m2 = __shfl(r1[2], b2); m3 = __shfl(r1[3], b2); }
                else if (w == 2) { m0 = __shfl(r2[0], b2); m1 = __shfl(r2[1], b2); m2 = __shfl(r2[2], b2); m3 = __shfl(r2[3], b2); }
                else             { m0 = __shfl(r3[0], b2); m1 = __shfl(r3[1], b2); m2 = __shfl(r3[2], b2); m3 = __shfl(r3[3], b2); }
                act[0] &= ~m0; act[1] &= ~m1; act[2] &= ~m2; act[3] &= ~m3;
            }
        }
        if (lane < 4) s_keep[lane] = keep[lane];
        if (lane == 0) {
            int total = __popcll(keep[0]) + __popcll(keep[1]) +
                        __popcll(keep[2]) + __popcll(keep[3]);
            s_base = (total > 0) ? atomicAdd(&pcnt[b], total) : 0;
        }
    }
    __syncthreads();
    if (tid < M_TOP) {
        unsigned long long kw = s_keep[tid >> 6];
        if ((kw >> (tid & 63)) & 1ull) {
            int pos = s_base;
            for (int w = 0; w < (tid >> 6); w++) pos += __popcll(s_keep[w]);
            pos += __popcll(kw & ((1ull << (tid & 63)) - 1ull));
            cmpval[(size_t)b * M + pos] = s_sc[tid];
            cmpidx[(size_t)b * M + pos] = c * M_TOP + tid;
        }
    }
}

// ---------------- Kernel E: top-200 of positives -> compact (val,idx) list ----------
__global__ __launch_bounds__(256) void gtop_kernel(
        const float* __restrict__ cmpval, const int* __restrict__ cmpidx,
        const int* __restrict__ pcnt, float* __restrict__ gl_val,
        int* __restrict__ gl_idx, int* __restrict__ gl_cnt, int M) {
    int b = blockIdx.x;
    int tid = threadIdx.x;
    int P = pcnt[b];
    const float* cv = cmpval + (size_t)b * M;
    const int*   ci = cmpidx + (size_t)b * M;
    if (P <= M_TOP) {
        for (int i = tid; i < P; i += 256) {
            gl_val[b * M_TOP + i] = cv[i];
            gl_idx[b * M_TOP + i] = ci[i];
        }
        if (tid == 0) gl_cnt[b] = P;
        return;
    }
    __shared__ uint32_t hist[256];
    __shared__ uint32_t s_prefix, s_want;
    __shared__ int tiebuf[256];
    __shared__ uint32_t ntie, wcnt;
    __shared__ int cutoff;
    if (tid == 0) { s_prefix = 0; s_want = M_TOP; }
    for (int pass = 0; pass < 4; pass++) {
        hist[tid] = 0;
        __syncthreads();
        uint32_t prefix = s_prefix;
        int shift = 24 - 8 * pass;
        for (int i = tid; i < P; i += 256) {
            uint32_t k = fkey(cv[i]);
            bool ok = (pass == 0) || ((k >> (shift + 8)) == (prefix >> (shift + 8)));
            if (ok) atomicAdd(&hist[(k >> shift) & 255u], 1u);
        }
        __syncthreads();
        if (tid == 0) {
            uint32_t want = s_want, cum = 0; int bin = 0;
            for (int bb = 255; bb >= 0; bb--) {
                if (cum + hist[bb] >= want) { bin = bb; break; }
                cum += hist[bb];
            }
            s_want = want - cum;
            s_prefix = prefix | ((uint32_t)bin << shift);
        }
        __syncthreads();
    }
    uint32_t kth = s_prefix, rfin = s_want;
    if (tid == 0) { ntie = 0; cutoff = -1; wcnt = 0; }
    __syncthreads();
    for (int i = tid; i < P; i += 256) {
        if (fkey(cv[i]) == kth) { uint32_t p = atomicAdd(&ntie, 1u); if (p < 256) tiebuf[p] = ci[i]; }
    }
    __syncthreads();
    uint32_t nt = min(ntie, 256u);
    if (tid < (int)nt) {
        int mine = tiebuf[tid];
        uint32_t rk = 0;
        for (uint32_t j = 0; j < nt; j++) if (tiebuf[j] < mine) rk++;
        if (rk == rfin - 1) cutoff = mine;
    }
    __syncthreads();
    int cut = cutoff;
    for (int i = tid; i < P; i += 256) {
        uint32_t k = fkey(cv[i]);
        if (k > kth || (k == kth && ci[i] <= cut)) {
            uint32_t p = atomicAdd(&wcnt, 1u);
            gl_val[b * M_TOP + p] = cv[i];
            gl_idx[b * M_TOP + p] = ci[i];
        }
    }
    if (tid == 0) gl_cnt[b] = M_TOP;
}

// ---------------- Kernel F: per-class sort + FULL output write (no memset) ----------
__global__ __launch_bounds__(256) void out_kernel(
        const float* __restrict__ gl_val, const int* __restrict__ gl_idx,
        const int* __restrict__ gl_cnt, const float* __restrict__ cand,
        float* __restrict__ out, int C, int Cm1) {
    int row = blockIdx.x;   // b*C + cc
    int b = row / C, cc = row % C;
    int tid = threadIdx.x;
    size_t oslab = (size_t)row * M_TOP * 5;
    if (cc == 0) {
        for (int i = tid; i < M_TOP * 5; i += 256) out[oslab + i] = 0.0f;
        return;
    }
    int c = cc - 1;
    __shared__ float lv[M_TOP];
    __shared__ int   lm[M_TOP];
    __shared__ uint32_t nloc;
    if (tid == 0) nloc = 0;
    __syncthreads();
    int cnt = gl_cnt[b];
    for (int i = tid; i < cnt; i += 256) {
        int idx = gl_idx[b * M_TOP + i];
        if (idx / M_TOP == c) {
            uint32_t p = atomicAdd(&nloc, 1u);
            lv[p] = gl_val[b * M_TOP + i];
            lm[p] = idx % M_TOP;
        }
    }
    __syncthreads();
    int nc = (int)nloc;
    if (tid < M_TOP) {
        if (tid < nc) {
            float v = lv[tid]; int m = lm[tid];
            int rk = 0;
            for (int j = 0; j < nc; j++)
                if (lv[j] > v || (lv[j] == v && lm[j] < m)) rk++;
            float4 bb = ((const float4*)cand)[((size_t)(b * Cm1 + c)) * M_TOP + m];
            size_t o = oslab + (size_t)rk * 5;
            out[o] = v; out[o + 1] = bb.x; out[o + 2] = bb.y;
            out[o + 3] = bb.z; out[o + 4] = bb.w;
        } else {
            size_t o = oslab + (size_t)tid * 5;
            out[o] = 0.f; out[o + 1] = 0.f; out[o + 2] = 0.f;
            out[o + 3] = 0.f; out[o + 4] = 0.f;
        }
    }
}

extern "C" void kernel_launch(void* const* d_in, const int* in_sizes, int n_in,
                              void* d_out, int out_size, void* d_ws, size_t ws_size,
                              hipStream_t stream) {
    const float* loc  = (const float*)d_in[0];
    const float* conf = (const float*)d_in[1];
    const float* dbox = (const float*)d_in[2];
    int N   = in_sizes[2] / 4;
    int B   = in_sizes[0] / (4 * N);
    int C   = in_sizes[1] / (B * N);
    int Cm1 = C - 1;
    int M   = Cm1 * M_TOP;                 // 16000 per batch

    char* ws = (char*)d_ws;
    size_t off = 0;
    auto alloc = [&](size_t bytes) -> char* {
        char* p = ws + off;
        off = (off + bytes + 255) & ~(size_t)255;
        return p;
    };
    float* sc     = (float*)alloc((size_t)B * Cm1 * N * sizeof(float));
    float* cand   = (float*)alloc((size_t)B * M * 4 * sizeof(float));
    int*   pcnt   = (int*)alloc((size_t)B * sizeof(int));
    float* cmpval = (float*)alloc((size_t)B * M * sizeof(float));
    int*   cmpidx = (int*)alloc((size_t)B * M * sizeof(int));
    float* gl_val = (float*)alloc((size_t)B * M_TOP * sizeof(float));
    int*   gl_idx = (int*)alloc((size_t)B * M_TOP * sizeof(int));
    int*   gl_cnt = (int*)alloc((size_t)B * sizeof(int));

    int bn = B * N;
    hipMemsetAsync(pcnt, 0, (size_t)B * sizeof(int), stream);
    softmax_kernel<<<(bn + SM_ROWS - 1) / SM_ROWS, SM_ROWS, 0, stream>>>(conf, sc, B, N, C);
    topk_kernel<<<B * Cm1, TK_BS, 0, stream>>>(sc, loc, dbox, cand, cmpval, cmpidx, pcnt,
                                               B, N, Cm1, M);
    gtop_kernel<<<B, 256, 0, stream>>>(cmpval, cmpidx, pcnt, gl_val, gl_idx, gl_cnt, M);
    out_kernel<<<B * C, 256, 0, stream>>>(gl_val, gl_idx, gl_cnt, cand, (float*)d_out, C, Cm1);
}

// Round 12
// 299.867 us; speedup vs baseline: 1.2371x; 1.2371x over previous
//
#include <hip/hip_runtime.h>
#include <stdint.h>

#define CONF_T 0.01f
#define NMS_T  0.45f
#define M_TOP  200
#define TK_BS  256    // topk block size
#define TCAP   4096   // topk bracket buffer capacity (LDS)

typedef float float4u __attribute__((ext_vector_type(4), aligned(4)));

__device__ __forceinline__ uint32_t fkey(float f) {
    uint32_t u = __float_as_uint(f);
    return (u & 0x80000000u) ? ~u : (u | 0x80000000u);
}
__device__ __forceinline__ float fkey_inv(uint32_t k) {
    uint32_t u = (k & 0x80000000u) ? (k & 0x7FFFFFFFu) : ~k;
    return __uint_as_float(u);
}

// Parallel suffix-scan bin selection over nb bins (nb multiple of 256).
// Wave-level suffix scan via shfl_down doubling + cross-wave combine: 2 barriers.
__device__ __forceinline__ void suffix_select(
        uint32_t* hist, uint32_t* wsum, int nb, uint32_t pref, int shift,
        uint32_t wantv, uint32_t* s_prefix, uint32_t* s_want) {
    int tid = threadIdx.x;
    int lane = tid & 63, w = tid >> 6;
    int bpt = nb >> 8;
    int base = tid * bpt;
    uint32_t loc = 0;
    for (int j = 0; j < bpt; j++) loc += hist[base + j];
    uint32_t sfx = loc;
    #pragma unroll
    for (int d = 1; d < 64; d <<= 1) {
        uint32_t y = __shfl_down(sfx, d);
        if (lane + d < 64) sfx += y;
    }
    if (lane == 0) wsum[w] = sfx;
    __syncthreads();
    uint32_t later = 0;
    for (int j = w + 1; j < TK_BS / 64; j++) later += wsum[j];
    uint32_t run = (sfx - loc) + later;
    for (int j = bpt - 1; j >= 0; j--) {
        uint32_t h = hist[base + j];
        uint32_t s2 = run + h;
        if (run < wantv && s2 >= wantv) {
            *s_prefix = pref | ((uint32_t)(base + j) << shift);
            *s_want   = wantv - run;
        }
        run = s2;
    }
    __syncthreads();
}

__device__ __forceinline__ float4 decode_box(float4 l, float4 d) {
    float cx = d.x + (l.x * 0.1f) * d.z;
    float cy = d.y + (l.y * 0.1f) * d.w;
    float w  = d.z * expf(l.z * 0.2f);
    float h  = d.w * expf(l.w * 0.2f);
    float x1 = cx - w * 0.5f, y1 = cy - h * 0.5f;
    float x2 = x1 + w, y2 = y1 + h;
    float4 o;
    o.x = fminf(fmaxf(x1, 0.f), 1.f);
    o.y = fminf(fmaxf(y1, 0.f), 1.f);
    o.z = fminf(fmaxf(x2, 0.f), 1.f);
    o.w = fminf(fmaxf(y2, 0.f), 1.f);
    return o;
}

// ---------------- Kernel B: softmax + transpose (register-resident, no LDS) ----------
// Thread r holds its whole 81-float row in registers (20 dwordx4 + 1 dword,
// 4-byte-aligned vector loads). Same arithmetic order as the R8-passing
// version: sequential fmax, sequential sum of expf in class order, IEEE div.
// __launch_bounds__(256,4) caps VGPR <=128 -> 16 waves/CU (vs 7 LDS-bound).
__global__ __launch_bounds__(256, 4) void softmax_kernel(
        const float* __restrict__ conf, float* __restrict__ sc,
        int B, int N, int C) {
    int r = blockIdx.x * blockDim.x + threadIdx.x;
    if (r >= B * N) return;
    const float* p = conf + (size_t)r * 81;
    float v[81];
    #pragma unroll
    for (int i = 0; i < 20; i++) {
        float4u f = *(const float4u*)(p + 4 * i);
        v[4 * i] = f.x; v[4 * i + 1] = f.y; v[4 * i + 2] = f.z; v[4 * i + 3] = f.w;
    }
    v[80] = p[80];
    float m = v[0];
    #pragma unroll
    for (int c = 1; c < 81; c++) m = fmaxf(m, v[c]);
    float s = 0.f;
    #pragma unroll
    for (int c = 0; c < 81; c++) { float e = expf(v[c] - m); v[c] = e; s += e; }
    int b = r / N, n = r % N;
    float* obase = sc + ((size_t)b * (C - 1)) * N + n;
    #pragma unroll
    for (int c = 1; c < 81; c++) obase[(size_t)(c - 1) * N] = v[c] / s;
}

// ---------------- Kernel C: top-200 + inline decode + fused serial-wave NMS ----------
__global__ __launch_bounds__(TK_BS) void topk_kernel(
        const float* __restrict__ sc, const float* __restrict__ loc,
        const float* __restrict__ dbox,
        float* __restrict__ cand,
        float* __restrict__ cmpval, int* __restrict__ cmpidx,
        int* __restrict__ pcnt,
        int B, int N, int Cm1, int M) {
    const uint32_t KEYN1 = 0x407FFFFFu;        // fkey(-1.0f)
    const uint32_t BIN_N1 = KEYN1 >> 21;       // 0x203
    __shared__ __align__(16) uint32_t hist[2048];
    __shared__ __align__(16) uint32_t tk[TCAP];
    __shared__ int      tix[TCAP];
    __shared__ uint32_t wsum[TK_BS / 64];
    __shared__ uint32_t s_prefix, s_want;
    __shared__ uint32_t ngt, ntie, tcnt;
    __shared__ float    e_val[256];
    __shared__ int      e_idx[256];
    __shared__ int      tiebuf[256];
    __shared__ float    s_sc[M_TOP];
    __shared__ float    s_x1[M_TOP], s_y1[M_TOP], s_x2[M_TOP], s_y2[M_TOP];

    int row = blockIdx.x;                      // b*Cm1 + c
    int b = row / Cm1, c = row % Cm1;
    int tid = threadIdx.x;
    const float* v = sc + (size_t)row * N;
    const float4* v4 = (const float4*)v;
    int n4 = N >> 2;

    // ---- sample phase ----
    bool sampled = (N >= 2048) && ((N & 7) == 0);
    uint32_t lo_key = 0xFFFFFFFFu, hi_key = 0xFFFFFFFFu;
    if (sampled) {
        int stride = N >> 3;
        for (int s = 0; s < 8; s++) {
            float f = v[s * stride + tid];
            tk[s * 256 + tid] = fkey(f > CONF_T ? f : -1.0f);
        }
        for (int i = tid; i < 2048; i += TK_BS) hist[i] = 0;
        __syncthreads();
        for (int i = tid; i < 2048; i += TK_BS) atomicAdd(&hist[tk[i] >> 21], 1u);
        __syncthreads();
        suffix_select(hist, wsum, 2048, 0u, 21, 3u, &s_prefix, &s_want);
        uint32_t h = s_prefix >> 21;
        suffix_select(hist, wsum, 2048, 0u, 21, 25u, &s_prefix, &s_want);
        uint32_t l = s_prefix >> 21;
        hi_key = ((h + 1) << 21) - 1u;
        lo_key = (l << 21) - 1u;
        sampled = (l > BIN_N1);
    }

    e_val[tid] = -1.0f; e_idx[tid] = tid;
    if (tid == 0) { ngt = 0; ntie = 0; tcnt = 0; }
    __syncthreads();

    bool ok = false;
    uint32_t G = 0, T = 0;
    if (sampled) {
        for (int i = tid; i < n4; i += TK_BS) {
            float4 f = v4[i];
            float mv[4] = { f.x > CONF_T ? f.x : -1.0f, f.y > CONF_T ? f.y : -1.0f,
                            f.z > CONF_T ? f.z : -1.0f, f.w > CONF_T ? f.w : -1.0f };
            #pragma unroll
            for (int j = 0; j < 4; j++) {
                uint32_t k = fkey(mv[j]);
                if (k > lo_key) {
                    int idx = 4 * i + j;
                    if (k > hi_key) {
                        uint32_t p = atomicAdd(&ngt, 1u);
                        if (p < 256) { e_val[p] = mv[j]; e_idx[p] = idx; }
                    } else {
                        uint32_t p = atomicAdd(&tcnt, 1u);
                        if (p < TCAP) { tk[p] = k; tix[p] = idx; }
                    }
                }
            }
        }
        for (int i = (n4 << 2) + tid; i < N; i += TK_BS) {
            float f = v[i];
            float mv = f > CONF_T ? f : -1.0f;
            uint32_t k = fkey(mv);
            if (k > lo_key) {
                if (k > hi_key) {
                    uint32_t p = atomicAdd(&ngt, 1u);
                    if (p < 256) { e_val[p] = mv; e_idx[p] = i; }
                } else {
                    uint32_t p = atomicAdd(&tcnt, 1u);
                    if (p < TCAP) { tk[p] = k; tix[p] = i; }
                }
            }
        }
        __syncthreads();
        G = ngt; T = tcnt;
        ok = (G <= (uint32_t)M_TOP) && (T <= (uint32_t)TCAP) &&
             (G + T >= (uint32_t)M_TOP);
    }

    uint32_t kth = KEYN1, rfin = 0;
    if (ok) {
        uint32_t want_t = (uint32_t)M_TOP - G;
        if (want_t > 0) {
            for (int i = tid; i < 2048; i += TK_BS) hist[i] = 0;
            __syncthreads();
            for (int i = tid; i < (int)T; i += TK_BS) atomicAdd(&hist[tk[i] >> 21], 1u);
            __syncthreads();
            suffix_select(hist, wsum, 2048, 0u, 21, want_t, &s_prefix, &s_want);
            uint32_t pre0 = s_prefix, w0 = s_want;
            uint32_t bb0 = pre0 >> 21;
            for (int i = tid; i < 2048; i += TK_BS) hist[i] = 0;
            __syncthreads();
            for (int i = tid; i < (int)T; i += TK_BS)
                if ((tk[i] >> 21) == bb0) atomicAdd(&hist[(tk[i] >> 10) & 2047u], 1u);
            __syncthreads();
            suffix_select(hist, wsum, 2048, pre0, 10, w0, &s_prefix, &s_want);
            uint32_t pre1 = s_prefix, w1 = s_want;
            for (int i = tid; i < 1024; i += TK_BS) hist[i] = 0;
            __syncthreads();
            for (int i = tid; i < (int)T; i += TK_BS)
                if ((tk[i] >> 10) == (pre1 >> 10)) atomicAdd(&hist[tk[i] & 1023u], 1u);
            __syncthreads();
            suffix_select(hist, wsum, 1024, pre1, 0, w1, &s_prefix, &s_want);
            kth = s_prefix; rfin = s_want;
            for (int i = tid; i < (int)T; i += TK_BS) {
                uint32_t k = tk[i];
                if (k > kth) {
                    uint32_t p = atomicAdd(&ngt, 1u);
                    if (p < 256) { e_val[p] = fkey_inv(k); e_idx[p] = tix[i]; }
                } else if (k == kth) {
                    uint32_t p = atomicAdd(&ntie, 1u);
                    if (p < 256) tiebuf[p] = tix[i];
                }
            }
            __syncthreads();
        }
    } else {
        // ---- fallback: exact 2-sweep histogram path ----
        e_val[tid] = -1.0f; e_idx[tid] = tid;
        if (tid == 0) { ngt = 0; ntie = 0; tcnt = 0; }
        for (int i = tid; i < 2048; i += TK_BS) hist[i] = 0;
        __syncthreads();
        for (int i = tid; i < n4; i += TK_BS) {
            float4 f = v4[i];
            atomicAdd(&hist[fkey(f.x > CONF_T ? f.x : -1.0f) >> 21], 1u);
            atomicAdd(&hist[fkey(f.y > CONF_T ? f.y : -1.0f) >> 21], 1u);
            atomicAdd(&hist[fkey(f.z > CONF_T ? f.z : -1.0f) >> 21], 1u);
            atomicAdd(&hist[fkey(f.w > CONF_T ? f.w : -1.0f) >> 21], 1u);
        }
        for (int i = (n4 << 2) + tid; i < N; i += TK_BS)
            atomicAdd(&hist[fkey(v[i] > CONF_T ? v[i] : -1.0f) >> 21], 1u);
        __syncthreads();
        suffix_select(hist, wsum, 2048, 0u, 21, M_TOP, &s_prefix, &s_want);
        uint32_t b0 = s_prefix >> 21;
        uint32_t want1 = s_want;
        bool collect_ties = (b0 != BIN_N1);
        for (int i = tid; i < N; i += TK_BS) {
            float f = v[i];
            float mv = f > CONF_T ? f : -1.0f;
            uint32_t k = fkey(mv);
            uint32_t bin = k >> 21;
            if (bin > b0) {
                uint32_t p = atomicAdd(&ngt, 1u);
                if (p < 256) { e_val[p] = mv; e_idx[p] = i; }
            } else if (bin == b0 && collect_ties) {
                uint32_t p = atomicAdd(&tcnt, 1u);
                if (p < TCAP) { tk[p] = k; tix[p] = i; }
            }
        }
        __syncthreads();
        if (collect_ties && tcnt <= TCAP) {
            int Tl = (int)tcnt;
            for (int i = tid; i < 2048; i += TK_BS) hist[i] = 0;
            __syncthreads();
            for (int i = tid; i < Tl; i += TK_BS) atomicAdd(&hist[(tk[i] >> 10) & 2047u], 1u);
            __syncthreads();
            suffix_select(hist, wsum, 2048, b0 << 21, 10, want1, &s_prefix, &s_want);
            uint32_t pre2 = s_prefix; uint32_t want2 = s_want;
            uint32_t b1 = (pre2 >> 10) & 2047u;
            for (int i = tid; i < 1024; i += TK_BS) hist[i] = 0;
            __syncthreads();
            for (int i = tid; i < Tl; i += TK_BS)
                if (((tk[i] >> 10) & 2047u) == b1) atomicAdd(&hist[tk[i] & 1023u], 1u);
            __syncthreads();
            suffix_select(hist, wsum, 1024, pre2, 0, want2, &s_prefix, &s_want);
            kth = s_prefix; rfin = s_want;
            for (int i = tid; i < Tl; i += TK_BS) {
                uint32_t k = tk[i];
                if (k > kth) {
                    uint32_t p = atomicAdd(&ngt, 1u);
                    if (p < 256) { e_val[p] = fkey_inv(k); e_idx[p] = tix[i]; }
                } else if (k == kth) {
                    uint32_t p = atomicAdd(&ntie, 1u);
                    if (p < 256) tiebuf[p] = tix[i];
                }
            }
            __syncthreads();
        } else if (collect_ties) {
            const int shifts[2] = {10, 0};
            const int nbins_[2] = {2048, 1024};
            if (tid == 0) { s_prefix = b0 << 21; s_want = want1; }
            __syncthreads();
            for (int lev = 0; lev < 2; lev++) {
                int shift = shifts[lev];
                int nb = nbins_[lev];
                uint32_t bmask = (uint32_t)nb - 1u;
                uint32_t pref = s_prefix, wantv = s_want;
                uint32_t pmask = 0xFFFFFFFFu << (shift + ((nb == 2048) ? 11 : 10));
                for (int i = tid; i < nb; i += TK_BS) hist[i] = 0;
                __syncthreads();
                for (int i = tid; i < N; i += TK_BS) {
                    float f = v[i];
                    uint32_t k = fkey(f > CONF_T ? f : -1.0f);
                    if ((k & pmask) == (pref & pmask)) atomicAdd(&hist[(k >> shift) & bmask], 1u);
                }
                __syncthreads();
                suffix_select(hist, wsum, nb, pref, shift, wantv, &s_prefix, &s_want);
            }
            kth = s_prefix; rfin = s_want;
            for (int i = tid; i < N; i += TK_BS) {
                float f = v[i];
                float mv = f > CONF_T ? f : -1.0f;
                uint32_t k = fkey(mv);
                if ((k >> 21) == b0) {
                    if (k > kth) {
                        uint32_t p = atomicAdd(&ngt, 1u);
                        if (p < 256) { e_val[p] = mv; e_idx[p] = i; }
                    } else if (k == kth) {
                        uint32_t p = atomicAdd(&ntie, 1u);
                        if (p < 256) tiebuf[p] = i;
                    }
                }
            }
            __syncthreads();
        }
    }

    // ---- ties, rank order, inline box decode -> LDS + cand ----
    uint32_t gcount = min(ngt, (uint32_t)M_TOP);
    uint32_t nt = min(ntie, 256u);
    if (tid < (int)nt) {
        int mine = tiebuf[tid];
        uint32_t rk = 0;
        for (uint32_t j = 0; j < nt; j++) if (tiebuf[j] < mine) rk++;
        if (rk < rfin) {
            uint32_t slot = gcount + rk;
            if (slot < M_TOP) { e_val[slot] = fkey_inv(kth); e_idx[slot] = mine; }
        }
    }
    __syncthreads();
    if (tid < M_TOP) {
        float mv = e_val[tid]; int mi = e_idx[tid];
        uint32_t mk = fkey(mv);
        uint32_t rk = 0;
        for (int j = 0; j < M_TOP; j++) {
            uint32_t jk = fkey(e_val[j]); int ji = e_idx[j];
            if (jk > mk || (jk == mk && ji < mi)) rk++;
        }
        float4 l = ((const float4*)loc)[(size_t)b * N + mi];
        float4 d = ((const float4*)dbox)[mi];
        float4 bx = decode_box(l, d);
        ((float4*)cand)[(size_t)row * M_TOP + rk] = bx;   // for out_kernel gather
        s_sc[rk] = mv;
        s_x1[rk] = bx.x; s_y1[rk] = bx.y; s_x2[rk] = bx.z; s_y2[rk] = bx.w;
    }
    __syncthreads();

    // ---- fused greedy NMS + compaction on wave 0 (R10-proven serial form) ----
    if (tid < 64) {
        int lane = tid;
        float x1[4], y1[4], x2[4], y2[4], ar[4], sv[4];
        int act[4], kf[4];
        #pragma unroll
        for (int s = 0; s < 4; s++) {
            int j = s * 64 + lane;
            if (j < M_TOP) {
                x1[s] = s_x1[j]; y1[s] = s_y1[j]; x2[s] = s_x2[j]; y2[s] = s_y2[j];
                ar[s] = (x2[s] - x1[s]) * (y2[s] - y1[s]);
                sv[s] = s_sc[j];
            } else { x1[s]=0.f; y1[s]=0.f; x2[s]=0.f; y2[s]=0.f; ar[s]=0.f; sv[s]=-1.0f; }
            act[s] = (sv[s] > CONF_T) ? 1 : 0;
            kf[s] = 0;
        }
        #pragma unroll
        for (int si = 0; si < 4; si++) {
            int lim = M_TOP - si * 64; if (lim > 64) lim = 64;
            for (int li = 0; li < lim; li++) {
                int a = __shfl(act[si], li);
                if (a) {
                    if (lane == li) kf[si] = 1;
                    float bx1 = __shfl(x1[si], li);
                    float by1 = __shfl(y1[si], li);
                    float bx2 = __shfl(x2[si], li);
                    float by2 = __shfl(y2[si], li);
                    float bar = __shfl(ar[si], li);
                    #pragma unroll
                    for (int s = 0; s < 4; s++) {
                        float xx1 = fmaxf(bx1, x1[s]);
                        float yy1 = fmaxf(by1, y1[s]);
                        float xx2 = fminf(bx2, x2[s]);
                        float yy2 = fminf(by2, y2[s]);
                        float inter = fmaxf(xx2 - xx1, 0.f) * fmaxf(yy2 - yy1, 0.f);
                        float uni = (ar[s] - inter) + bar;
                        float iou = inter / uni;
                        if (!(iou <= NMS_T)) act[s] = 0;   // NaN suppresses
                    }
                }
            }
        }
        unsigned long long ball[4];
        int total = 0;
        #pragma unroll
        for (int s = 0; s < 4; s++) { ball[s] = __ballot(kf[s] != 0); total += (int)__popcll(ball[s]); }
        int base = 0;
        if (lane == 0 && total > 0) base = atomicAdd(&pcnt[b], total);
        base = __shfl(base, 0);
        unsigned long long lower = (lane == 0) ? 0ull : (~0ull >> (64 - lane));
        int off = base;
        #pragma unroll
        for (int s = 0; s < 4; s++) {
            if (kf[s]) {
                int pos = off + (int)__popcll(ball[s] & lower);
                cmpval[(size_t)b * M + pos] = sv[s];
                cmpidx[(size_t)b * M + pos] = c * M_TOP + s * 64 + lane;
            }
            off += (int)__popcll(ball[s]);
        }
    }
}

// ---------------- Kernel E: top-200 of positives -> compact (val,idx) list ----------
__global__ __launch_bounds__(256) void gtop_kernel(
        const float* __restrict__ cmpval, const int* __restrict__ cmpidx,
        const int* __restrict__ pcnt, float* __restrict__ gl_val,
        int* __restrict__ gl_idx, int* __restrict__ gl_cnt, int M) {
    int b = blockIdx.x;
    int tid = threadIdx.x;
    int P = pcnt[b];
    const float* cv = cmpval + (size_t)b * M;
    const int*   ci = cmpidx + (size_t)b * M;
    if (P <= M_TOP) {
        for (int i = tid; i < P; i += 256) {
            gl_val[b * M_TOP + i] = cv[i];
            gl_idx[b * M_TOP + i] = ci[i];
        }
        if (tid == 0) gl_cnt[b] = P;
        return;
    }
    __shared__ uint32_t hist[256];
    __shared__ uint32_t s_prefix, s_want;
    __shared__ int tiebuf[256];
    __shared__ uint32_t ntie, wcnt;
    __shared__ int cutoff;
    if (tid == 0) { s_prefix = 0; s_want = M_TOP; }
    for (int pass = 0; pass < 4; pass++) {
        hist[tid] = 0;
        __syncthreads();
        uint32_t prefix = s_prefix;
        int shift = 24 - 8 * pass;
        for (int i = tid; i < P; i += 256) {
            uint32_t k = fkey(cv[i]);
            bool ok = (pass == 0) || ((k >> (shift + 8)) == (prefix >> (shift + 8)));
            if (ok) atomicAdd(&hist[(k >> shift) & 255u], 1u);
        }
        __syncthreads();
        if (tid == 0) {
            uint32_t want = s_want, cum = 0; int bin = 0;
            for (int bb = 255; bb >= 0; bb--) {
                if (cum + hist[bb] >= want) { bin = bb; break; }
                cum += hist[bb];
            }
            s_want = want - cum;
            s_prefix = prefix | ((uint32_t)bin << shift);
        }
        __syncthreads();
    }
    uint32_t kth = s_prefix, rfin = s_want;
    if (tid == 0) { ntie = 0; cutoff = -1; wcnt = 0; }
    __syncthreads();
    for (int i = tid; i < P; i += 256) {
        if (fkey(cv[i]) == kth) { uint32_t p = atomicAdd(&ntie, 1u); if (p < 256) tiebuf[p] = ci[i]; }
    }
    __syncthreads();
    uint32_t nt = min(ntie, 256u);
    if (tid < (int)nt) {
        int mine = tiebuf[tid];
        uint32_t rk = 0;
        for (uint32_t j = 0; j < nt; j++) if (tiebuf[j] < mine) rk++;
        if (rk == rfin - 1) cutoff = mine;
    }
    __syncthreads();
    int cut = cutoff;
    for (int i = tid; i < P; i += 256) {
        uint32_t k = fkey(cv[i]);
        if (k > kth || (k == kth && ci[i] <= cut)) {
            uint32_t p = atomicAdd(&wcnt, 1u);
            gl_val[b * M_TOP + p] = cv[i];
            gl_idx[b * M_TOP + p] = ci[i];
        }
    }
    if (tid == 0) gl_cnt[b] = M_TOP;
}

// ---------------- Kernel F: per-class sort + FULL output write (no memset) ----------
__global__ __launch_bounds__(256) void out_kernel(
        const float* __restrict__ gl_val, const int* __restrict__ gl_idx,
        const int* __restrict__ gl_cnt, const float* __restrict__ cand,
        float* __restrict__ out, int C, int Cm1) {
    int row = blockIdx.x;   // b*C + cc
    int b = row / C, cc = row % C;
    int tid = threadIdx.x;
    size_t oslab = (size_t)row * M_TOP * 5;
    if (cc == 0) {
        for (int i = tid; i < M_TOP * 5; i += 256) out[oslab + i] = 0.0f;
        return;
    }
    int c = cc - 1;
    __shared__ float lv[M_TOP];
    __shared__ int   lm[M_TOP];
    __shared__ uint32_t nloc;
    if (tid == 0) nloc = 0;
    __syncthreads();
    int cnt = gl_cnt[b];
    for (int i = tid; i < cnt; i += 256) {
        int idx = gl_idx[b * M_TOP + i];
        if (idx / M_TOP == c) {
            uint32_t p = atomicAdd(&nloc, 1u);
            lv[p] = gl_val[b * M_TOP + i];
            lm[p] = idx % M_TOP;
        }
    }
    __syncthreads();
    int nc = (int)nloc;
    if (tid < M_TOP) {
        if (tid < nc) {
            float v = lv[tid]; int m = lm[tid];
            int rk = 0;
            for (int j = 0; j < nc; j++)
                if (lv[j] > v || (lv[j] == v && lm[j] < m)) rk++;
            float4 bb = ((const float4*)cand)[((size_t)(b * Cm1 + c)) * M_TOP + m];
            size_t o = oslab + (size_t)rk * 5;
            out[o] = v; out[o + 1] = bb.x; out[o + 2] = bb.y;
            out[o + 3] = bb.z; out[o + 4] = bb.w;
        } else {
            size_t o = oslab + (size_t)tid * 5;
            out[o] = 0.f; out[o + 1] = 0.f; out[o + 2] = 0.f;
            out[o + 3] = 0.f; out[o + 4] = 0.f;
        }
    }
}

extern "C" void kernel_launch(void* const* d_in, const int* in_sizes, int n_in,
                              void* d_out, int out_size, void* d_ws, size_t ws_size,
                              hipStream_t stream) {
    const float* loc  = (const float*)d_in[0];
    const float* conf = (const float*)d_in[1];
    const float* dbox = (const float*)d_in[2];
    int N   = in_sizes[2] / 4;
    int B   = in_sizes[0] / (4 * N);
    int C   = in_sizes[1] / (B * N);
    int Cm1 = C - 1;
    int M   = Cm1 * M_TOP;                 // 16000 per batch

    char* ws = (char*)d_ws;
    size_t off = 0;
    auto alloc = [&](size_t bytes) -> char* {
        char* p = ws + off;
        off = (off + bytes + 255) & ~(size_t)255;
        return p;
    };
    float* sc     = (float*)alloc((size_t)B * Cm1 * N * sizeof(float));
    float* cand   = (float*)alloc((size_t)B * M * 4 * sizeof(float));
    int*   pcnt   = (int*)alloc((size_t)B * sizeof(int));
    float* cmpval = (float*)alloc((size_t)B * M * sizeof(float));
    int*   cmpidx = (int*)alloc((size_t)B * M * sizeof(int));
    float* gl_val = (float*)alloc((size_t)B * M_TOP * sizeof(float));
    int*   gl_idx = (int*)alloc((size_t)B * M_TOP * sizeof(int));
    int*   gl_cnt = (int*)alloc((size_t)B * sizeof(int));

    int bn = B * N;
    hipMemsetAsync(pcnt, 0, (size_t)B * sizeof(int), stream);
    softmax_kernel<<<(bn + 255) / 256, 256, 0, stream>>>(conf, sc, B, N, C);
    topk_kernel<<<B * Cm1, TK_BS, 0, stream>>>(sc, loc, dbox, cand, cmpval, cmpidx, pcnt,
                                               B, N, Cm1, M);
    gtop_kernel<<<B, 256, 0, stream>>>(cmpval, cmpidx, pcnt, gl_val, gl_idx, gl_cnt, M);
    out_kernel<<<B * C, 256, 0, stream>>>(gl_val, gl_idx, gl_cnt, cand, (float*)d_out, C, Cm1);
}

// Round 13
// 282.349 us; speedup vs baseline: 1.3139x; 1.0620x over previous
//
#include <hip/hip_runtime.h>
#include <stdint.h>

#define CONF_T 0.01f
#define NMS_T  0.45f
#define M_TOP  200
#define TK_BS  256    // topk block size
#define TCAP   2048   // topk bracket buffer capacity (LDS); overflow -> exact fallback

typedef float float4u __attribute__((ext_vector_type(4), aligned(4)));

__device__ __forceinline__ uint32_t fkey(float f) {
    uint32_t u = __float_as_uint(f);
    return (u & 0x80000000u) ? ~u : (u | 0x80000000u);
}
__device__ __forceinline__ float fkey_inv(uint32_t k) {
    uint32_t u = (k & 0x80000000u) ? (k & 0x7FFFFFFFu) : ~k;
    return __uint_as_float(u);
}

// Parallel suffix-scan bin selection over nb bins (nb multiple of 256).
// Wave-level suffix scan via shfl_down doubling + cross-wave combine: 2 barriers.
__device__ __forceinline__ void suffix_select(
        uint32_t* hist, uint32_t* wsum, int nb, uint32_t pref, int shift,
        uint32_t wantv, uint32_t* s_prefix, uint32_t* s_want) {
    int tid = threadIdx.x;
    int lane = tid & 63, w = tid >> 6;
    int bpt = nb >> 8;
    int base = tid * bpt;
    uint32_t loc = 0;
    for (int j = 0; j < bpt; j++) loc += hist[base + j];
    uint32_t sfx = loc;
    #pragma unroll
    for (int d = 1; d < 64; d <<= 1) {
        uint32_t y = __shfl_down(sfx, d);
        if (lane + d < 64) sfx += y;
    }
    if (lane == 0) wsum[w] = sfx;
    __syncthreads();
    uint32_t later = 0;
    for (int j = w + 1; j < TK_BS / 64; j++) later += wsum[j];
    uint32_t run = (sfx - loc) + later;
    for (int j = bpt - 1; j >= 0; j--) {
        uint32_t h = hist[base + j];
        uint32_t s2 = run + h;
        if (run < wantv && s2 >= wantv) {
            *s_prefix = pref | ((uint32_t)(base + j) << shift);
            *s_want   = wantv - run;
        }
        run = s2;
    }
    __syncthreads();
}

__device__ __forceinline__ float4 decode_box(float4 l, float4 d) {
    float cx = d.x + (l.x * 0.1f) * d.z;
    float cy = d.y + (l.y * 0.1f) * d.w;
    float w  = d.z * expf(l.z * 0.2f);
    float h  = d.w * expf(l.w * 0.2f);
    float x1 = cx - w * 0.5f, y1 = cy - h * 0.5f;
    float x2 = x1 + w, y2 = y1 + h;
    float4 o;
    o.x = fminf(fmaxf(x1, 0.f), 1.f);
    o.y = fminf(fmaxf(y1, 0.f), 1.f);
    o.z = fminf(fmaxf(x2, 0.f), 1.f);
    o.w = fminf(fmaxf(y2, 0.f), 1.f);
    return o;
}

// ---------------- Kernel B: softmax + transpose (register-resident) + pcnt init ------
__global__ __launch_bounds__(256, 4) void softmax_kernel(
        const float* __restrict__ conf, float* __restrict__ sc,
        int* __restrict__ pcnt, int B, int N, int C) {
    int r = blockIdx.x * blockDim.x + threadIdx.x;
    if (r < B) pcnt[r] = 0;                 // zero pcnt for the topk dispatch
    if (r >= B * N) return;
    const float* p = conf + (size_t)r * 81;
    float v[81];
    #pragma unroll
    for (int i = 0; i < 20; i++) {
        float4u f = *(const float4u*)(p + 4 * i);
        v[4 * i] = f.x; v[4 * i + 1] = f.y; v[4 * i + 2] = f.z; v[4 * i + 3] = f.w;
    }
    v[80] = p[80];
    float m = v[0];
    #pragma unroll
    for (int c = 1; c < 81; c++) m = fmaxf(m, v[c]);
    float s = 0.f;
    #pragma unroll
    for (int c = 0; c < 81; c++) { float e = expf(v[c] - m); v[c] = e; s += e; }
    int b = r / N, n = r % N;
    float* obase = sc + ((size_t)b * (C - 1)) * N + n;
    #pragma unroll
    for (int c = 1; c < 81; c++) obase[(size_t)(c - 1) * N] = v[c] / s;
}

// ---------------- Kernel C: top-200 + inline decode + fused serial-wave NMS ----------
__global__ __launch_bounds__(TK_BS) void topk_kernel(
        const float* __restrict__ sc, const float* __restrict__ loc,
        const float* __restrict__ dbox,
        float* __restrict__ cand,
        float* __restrict__ cmpval, int* __restrict__ cmpidx,
        int* __restrict__ pcnt,
        int B, int N, int Cm1, int M) {
    const uint32_t KEYN1 = 0x407FFFFFu;        // fkey(-1.0f)
    const uint32_t BIN_N1 = KEYN1 >> 21;       // 0x203
    __shared__ __align__(16) uint32_t hist[2048];
    __shared__ __align__(16) uint32_t tk[TCAP];
    __shared__ int      tix[TCAP];
    __shared__ uint32_t wsum[TK_BS / 64];
    __shared__ uint32_t s_prefix, s_want;
    __shared__ uint32_t ngt, ntie, tcnt;
    __shared__ float    e_val[256];
    __shared__ int      e_idx[256];
    __shared__ int      tiebuf[256];
    __shared__ float    s_sc[M_TOP];
    __shared__ float    s_x1[M_TOP], s_y1[M_TOP], s_x2[M_TOP], s_y2[M_TOP];

    int row = blockIdx.x;                      // b*Cm1 + c
    int b = row / Cm1, c = row % Cm1;
    int tid = threadIdx.x;
    const float* v = sc + (size_t)row * N;
    const float4* v4 = (const float4*)v;
    int n4 = N >> 2;

    // ---- sample phase (2048 strided samples; keys staged in tk[0..2047]) ----
    bool sampled = (N >= 2048) && ((N & 7) == 0);
    uint32_t lo_key = 0xFFFFFFFFu, hi_key = 0xFFFFFFFFu;
    if (sampled) {
        int stride = N >> 3;
        for (int s = 0; s < 8; s++) {
            float f = v[s * stride + tid];
            tk[s * 256 + tid] = fkey(f > CONF_T ? f : -1.0f);
        }
        for (int i = tid; i < 2048; i += TK_BS) hist[i] = 0;
        __syncthreads();
        for (int i = tid; i < 2048; i += TK_BS) atomicAdd(&hist[tk[i] >> 21], 1u);
        __syncthreads();
        suffix_select(hist, wsum, 2048, 0u, 21, 3u, &s_prefix, &s_want);
        uint32_t h = s_prefix >> 21;
        suffix_select(hist, wsum, 2048, 0u, 21, 25u, &s_prefix, &s_want);
        uint32_t l = s_prefix >> 21;
        hi_key = ((h + 1) << 21) - 1u;
        lo_key = (l << 21) - 1u;
        sampled = (l > BIN_N1);
    }

    e_val[tid] = -1.0f; e_idx[tid] = tid;
    if (tid == 0) { ngt = 0; ntie = 0; tcnt = 0; }
    __syncthreads();

    bool ok = false;
    uint32_t G = 0, T = 0;
    if (sampled) {
        for (int i = tid; i < n4; i += TK_BS) {
            float4 f = v4[i];
            float mv[4] = { f.x > CONF_T ? f.x : -1.0f, f.y > CONF_T ? f.y : -1.0f,
                            f.z > CONF_T ? f.z : -1.0f, f.w > CONF_T ? f.w : -1.0f };
            #pragma unroll
            for (int j = 0; j < 4; j++) {
                uint32_t k = fkey(mv[j]);
                if (k > lo_key) {
                    int idx = 4 * i + j;
                    if (k > hi_key) {
                        uint32_t p = atomicAdd(&ngt, 1u);
                        if (p < 256) { e_val[p] = mv[j]; e_idx[p] = idx; }
                    } else {
                        uint32_t p = atomicAdd(&tcnt, 1u);
                        if (p < TCAP) { tk[p] = k; tix[p] = idx; }
                    }
                }
            }
        }
        for (int i = (n4 << 2) + tid; i < N; i += TK_BS) {
            float f = v[i];
            float mv = f > CONF_T ? f : -1.0f;
            uint32_t k = fkey(mv);
            if (k > lo_key) {
                if (k > hi_key) {
                    uint32_t p = atomicAdd(&ngt, 1u);
                    if (p < 256) { e_val[p] = mv; e_idx[p] = i; }
                } else {
                    uint32_t p = atomicAdd(&tcnt, 1u);
                    if (p < TCAP) { tk[p] = k; tix[p] = i; }
                }
            }
        }
        __syncthreads();
        G = ngt; T = tcnt;
        ok = (G <= (uint32_t)M_TOP) && (T <= (uint32_t)TCAP) &&
             (G + T >= (uint32_t)M_TOP);
    }

    uint32_t kth = KEYN1, rfin = 0;
    if (ok) {
        uint32_t want_t = (uint32_t)M_TOP - G;
        if (want_t > 0) {
            for (int i = tid; i < 2048; i += TK_BS) hist[i] = 0;
            __syncthreads();
            for (int i = tid; i < (int)T; i += TK_BS) atomicAdd(&hist[tk[i] >> 21], 1u);
            __syncthreads();
            suffix_select(hist, wsum, 2048, 0u, 21, want_t, &s_prefix, &s_want);
            uint32_t pre0 = s_prefix, w0 = s_want;
            uint32_t bb0 = pre0 >> 21;
            for (int i = tid; i < 2048; i += TK_BS) hist[i] = 0;
            __syncthreads();
            for (int i = tid; i < (int)T; i += TK_BS)
                if ((tk[i] >> 21) == bb0) atomicAdd(&hist[(tk[i] >> 10) & 2047u], 1u);
            __syncthreads();
            suffix_select(hist, wsum, 2048, pre0, 10, w0, &s_prefix, &s_want);
            uint32_t pre1 = s_prefix, w1 = s_want;
            for (int i = tid; i < 1024; i += TK_BS) hist[i] = 0;
            __syncthreads();
            for (int i = tid; i < (int)T; i += TK_BS)
                if ((tk[i] >> 10) == (pre1 >> 10)) atomicAdd(&hist[tk[i] & 1023u], 1u);
            __syncthreads();
            suffix_select(hist, wsum, 1024, pre1, 0, w1, &s_prefix, &s_want);
            kth = s_prefix; rfin = s_want;
            for (int i = tid; i < (int)T; i += TK_BS) {
                uint32_t k = tk[i];
                if (k > kth) {
                    uint32_t p = atomicAdd(&ngt, 1u);
                    if (p < 256) { e_val[p] = fkey_inv(k); e_idx[p] = tix[i]; }
                } else if (k == kth) {
                    uint32_t p = atomicAdd(&ntie, 1u);
                    if (p < 256) tiebuf[p] = tix[i];
                }
            }
            __syncthreads();
        }
    } else {
        // ---- fallback: exact 2-sweep histogram path ----
        e_val[tid] = -1.0f; e_idx[tid] = tid;
        if (tid == 0) { ngt = 0; ntie = 0; tcnt = 0; }
        for (int i = tid; i < 2048; i += TK_BS) hist[i] = 0;
        __syncthreads();
        for (int i = tid; i < n4; i += TK_BS) {
            float4 f = v4[i];
            atomicAdd(&hist[fkey(f.x > CONF_T ? f.x : -1.0f) >> 21], 1u);
            atomicAdd(&hist[fkey(f.y > CONF_T ? f.y : -1.0f) >> 21], 1u);
            atomicAdd(&hist[fkey(f.z > CONF_T ? f.z : -1.0f) >> 21], 1u);
            atomicAdd(&hist[fkey(f.w > CONF_T ? f.w : -1.0f) >> 21], 1u);
        }
        for (int i = (n4 << 2) + tid; i < N; i += TK_BS)
            atomicAdd(&hist[fkey(v[i] > CONF_T ? v[i] : -1.0f) >> 21], 1u);
        __syncthreads();
        suffix_select(hist, wsum, 2048, 0u, 21, M_TOP, &s_prefix, &s_want);
        uint32_t b0 = s_prefix >> 21;
        uint32_t want1 = s_want;
        bool collect_ties = (b0 != BIN_N1);
        for (int i = tid; i < N; i += TK_BS) {
            float f = v[i];
            float mv = f > CONF_T ? f : -1.0f;
            uint32_t k = fkey(mv);
            uint32_t bin = k >> 21;
            if (bin > b0) {
                uint32_t p = atomicAdd(&ngt, 1u);
                if (p < 256) { e_val[p] = mv; e_idx[p] = i; }
            } else if (bin == b0 && collect_ties) {
                uint32_t p = atomicAdd(&tcnt, 1u);
                if (p < TCAP) { tk[p] = k; tix[p] = i; }
            }
        }
        __syncthreads();
        if (collect_ties && tcnt <= TCAP) {
            int Tl = (int)tcnt;
            for (int i = tid; i < 2048; i += TK_BS) hist[i] = 0;
            __syncthreads();
            for (int i = tid; i < Tl; i += TK_BS) atomicAdd(&hist[(tk[i] >> 10) & 2047u], 1u);
            __syncthreads();
            suffix_select(hist, wsum, 2048, b0 << 21, 10, want1, &s_prefix, &s_want);
            uint32_t pre2 = s_prefix; uint32_t want2 = s_want;
            uint32_t b1 = (pre2 >> 10) & 2047u;
            for (int i = tid; i < 1024; i += TK_BS) hist[i] = 0;
            __syncthreads();
            for (int i = tid; i < Tl; i += TK_BS)
                if (((tk[i] >> 10) & 2047u) == b1) atomicAdd(&hist[tk[i] & 1023u], 1u);
            __syncthreads();
            suffix_select(hist, wsum, 1024, pre2, 0, want2, &s_prefix, &s_want);
            kth = s_prefix; rfin = s_want;
            for (int i = tid; i < Tl; i += TK_BS) {
                uint32_t k = tk[i];
                if (k > kth) {
                    uint32_t p = atomicAdd(&ngt, 1u);
                    if (p < 256) { e_val[p] = fkey_inv(k); e_idx[p] = tix[i]; }
                } else if (k == kth) {
                    uint32_t p = atomicAdd(&ntie, 1u);
                    if (p < 256) tiebuf[p] = tix[i];
                }
            }
            __syncthreads();
        } else if (collect_ties) {
            const int shifts[2] = {10, 0};
            const int nbins_[2] = {2048, 1024};
            if (tid == 0) { s_prefix = b0 << 21; s_want = want1; }
            __syncthreads();
            for (int lev = 0; lev < 2; lev++) {
                int shift = shifts[lev];
                int nb = nbins_[lev];
                uint32_t bmask = (uint32_t)nb - 1u;
                uint32_t pref = s_prefix, wantv = s_want;
                uint32_t pmask = 0xFFFFFFFFu << (shift + ((nb == 2048) ? 11 : 10));
                for (int i = tid; i < nb; i += TK_BS) hist[i] = 0;
                __syncthreads();
                for (int i = tid; i < N; i += TK_BS) {
                    float f = v[i];
                    uint32_t k = fkey(f > CONF_T ? f : -1.0f);
                    if ((k & pmask) == (pref & pmask)) atomicAdd(&hist[(k >> shift) & bmask], 1u);
                }
                __syncthreads();
                suffix_select(hist, wsum, nb, pref, shift, wantv, &s_prefix, &s_want);
            }
            kth = s_prefix; rfin = s_want;
            for (int i = tid; i < N; i += TK_BS) {
                float f = v[i];
                float mv = f > CONF_T ? f : -1.0f;
                uint32_t k = fkey(mv);
                if ((k >> 21) == b0) {
                    if (k > kth) {
                        uint32_t p = atomicAdd(&ngt, 1u);
                        if (p < 256) { e_val[p] = mv; e_idx[p] = i; }
                    } else if (k == kth) {
                        uint32_t p = atomicAdd(&ntie, 1u);
                        if (p < 256) tiebuf[p] = i;
                    }
                }
            }
            __syncthreads();
        }
    }

    // ---- ties, rank order, inline box decode -> LDS + cand ----
    uint32_t gcount = min(ngt, (uint32_t)M_TOP);
    uint32_t nt = min(ntie, 256u);
    if (tid < (int)nt) {
        int mine = tiebuf[tid];
        uint32_t rk = 0;
        for (uint32_t j = 0; j < nt; j++) if (tiebuf[j] < mine) rk++;
        if (rk < rfin) {
            uint32_t slot = gcount + rk;
            if (slot < M_TOP) { e_val[slot] = fkey_inv(kth); e_idx[slot] = mine; }
        }
    }
    __syncthreads();
    if (tid < M_TOP) {
        float mv = e_val[tid]; int mi = e_idx[tid];
        uint32_t mk = fkey(mv);
        uint32_t rk = 0;
        for (int j = 0; j < M_TOP; j++) {
            uint32_t jk = fkey(e_val[j]); int ji = e_idx[j];
            if (jk > mk || (jk == mk && ji < mi)) rk++;
        }
        float4 l = ((const float4*)loc)[(size_t)b * N + mi];
        float4 d = ((const float4*)dbox)[mi];
        float4 bx = decode_box(l, d);
        ((float4*)cand)[(size_t)row * M_TOP + rk] = bx;   // for out_kernel gather
        s_sc[rk] = mv;
        s_x1[rk] = bx.x; s_y1[rk] = bx.y; s_x2[rk] = bx.z; s_y2[rk] = bx.w;
    }
    __syncthreads();

    // ---- fused greedy NMS + compaction on wave 0 (serial-wave form) ----
    if (tid < 64) {
        int lane = tid;
        float x1[4], y1[4], x2[4], y2[4], ar[4], sv[4];
        int act[4], kf[4];
        #pragma unroll
        for (int s = 0; s < 4; s++) {
            int j = s * 64 + lane;
            if (j < M_TOP) {
                x1[s] = s_x1[j]; y1[s] = s_y1[j]; x2[s] = s_x2[j]; y2[s] = s_y2[j];
                ar[s] = (x2[s] - x1[s]) * (y2[s] - y1[s]);
                sv[s] = s_sc[j];
            } else { x1[s]=0.f; y1[s]=0.f; x2[s]=0.f; y2[s]=0.f; ar[s]=0.f; sv[s]=-1.0f; }
            act[s] = (sv[s] > CONF_T) ? 1 : 0;
            kf[s] = 0;
        }
        #pragma unroll
        for (int si = 0; si < 4; si++) {
            int lim = M_TOP - si * 64; if (lim > 64) lim = 64;
            for (int li = 0; li < lim; li++) {
                int a = __shfl(act[si], li);
                if (a) {
                    if (lane == li) kf[si] = 1;
                    float bx1 = __shfl(x1[si], li);
                    float by1 = __shfl(y1[si], li);
                    float bx2 = __shfl(x2[si], li);
                    float by2 = __shfl(y2[si], li);
                    float bar = __shfl(ar[si], li);
                    #pragma unroll
                    for (int s = 0; s < 4; s++) {
                        float xx1 = fmaxf(bx1, x1[s]);
                        float yy1 = fmaxf(by1, y1[s]);
                        float xx2 = fminf(bx2, x2[s]);
                        float yy2 = fminf(by2, y2[s]);
                        float inter = fmaxf(xx2 - xx1, 0.f) * fmaxf(yy2 - yy1, 0.f);
                        float uni = (ar[s] - inter) + bar;
                        float iou = inter / uni;
                        if (!(iou <= NMS_T)) act[s] = 0;   // NaN suppresses
                    }
                }
            }
        }
        unsigned long long ball[4];
        int total = 0;
        #pragma unroll
        for (int s = 0; s < 4; s++) { ball[s] = __ballot(kf[s] != 0); total += (int)__popcll(ball[s]); }
        int base = 0;
        if (lane == 0 && total > 0) base = atomicAdd(&pcnt[b], total);
        base = __shfl(base, 0);
        unsigned long long lower = (lane == 0) ? 0ull : (~0ull >> (64 - lane));
        int off = base;
        #pragma unroll
        for (int s = 0; s < 4; s++) {
            if (kf[s]) {
                int pos = off + (int)__popcll(ball[s] & lower);
                cmpval[(size_t)b * M + pos] = sv[s];
                cmpidx[(size_t)b * M + pos] = c * M_TOP + s * 64 + lane;
            }
            off += (int)__popcll(ball[s]);
        }
    }
}

// ---------------- Kernel E: top-200 of positives -> compact (val,idx) list ----------
#define GT_BS 1024
__global__ __launch_bounds__(GT_BS) void gtop_kernel(
        const float* __restrict__ cmpval, const int* __restrict__ cmpidx,
        const int* __restrict__ pcnt, float* __restrict__ gl_val,
        int* __restrict__ gl_idx, int* __restrict__ gl_cnt, int M) {
    int b = blockIdx.x;
    int tid = threadIdx.x;
    int P = pcnt[b];
    const float* cv = cmpval + (size_t)b * M;
    const int*   ci = cmpidx + (size_t)b * M;
    if (P <= M_TOP) {
        for (int i = tid; i < P; i += GT_BS) {
            gl_val[b * M_TOP + i] = cv[i];
            gl_idx[b * M_TOP + i] = ci[i];
        }
        if (tid == 0) gl_cnt[b] = P;
        return;
    }
    __shared__ uint32_t hist[256];
    __shared__ uint32_t s_prefix, s_want;
    __shared__ int tiebuf[256];
    __shared__ uint32_t ntie, wcnt;
    __shared__ int cutoff;
    if (tid == 0) { s_prefix = 0; s_want = M_TOP; }
    for (int pass = 0; pass < 4; pass++) {
        if (tid < 256) hist[tid] = 0;
        __syncthreads();
        uint32_t prefix = s_prefix;
        int shift = 24 - 8 * pass;
        for (int i = tid; i < P; i += GT_BS) {
            uint32_t k = fkey(cv[i]);
            bool ok = (pass == 0) || ((k >> (shift + 8)) == (prefix >> (shift + 8)));
            if (ok) atomicAdd(&hist[(k >> shift) & 255u], 1u);
        }
        __syncthreads();
        if (tid == 0) {
            uint32_t want = s_want, cum = 0; int bin = 0;
            for (int bb = 255; bb >= 0; bb--) {
                if (cum + hist[bb] >= want) { bin = bb; break; }
                cum += hist[bb];
            }
            s_want = want - cum;
            s_prefix = prefix | ((uint32_t)bin << shift);
        }
        __syncthreads();
    }
    uint32_t kth = s_prefix, rfin = s_want;
    if (tid == 0) { ntie = 0; cutoff = -1; wcnt = 0; }
    __syncthreads();
    for (int i = tid; i < P; i += GT_BS) {
        if (fkey(cv[i]) == kth) { uint32_t p = atomicAdd(&ntie, 1u); if (p < 256) tiebuf[p] = ci[i]; }
    }
    __syncthreads();
    uint32_t nt = min(ntie, 256u);
    if (tid < (int)nt) {
        int mine = tiebuf[tid];
        uint32_t rk = 0;
        for (uint32_t j = 0; j < nt; j++) if (tiebuf[j] < mine) rk++;
        if (rk == rfin - 1) cutoff = mine;
    }
    __syncthreads();
    int cut = cutoff;
    for (int i = tid; i < P; i += GT_BS) {
        uint32_t k = fkey(cv[i]);
        if (k > kth || (k == kth && ci[i] <= cut)) {
            uint32_t p = atomicAdd(&wcnt, 1u);
            gl_val[b * M_TOP + p] = cv[i];
            gl_idx[b * M_TOP + p] = ci[i];
        }
    }
    if (tid == 0) gl_cnt[b] = M_TOP;
}

// ---------------- Kernel F: per-class sort + FULL output write (no memset) ----------
__global__ __launch_bounds__(256) void out_kernel(
        const float* __restrict__ gl_val, const int* __restrict__ gl_idx,
        const int* __restrict__ gl_cnt, const float* __restrict__ cand,
        float* __restrict__ out, int C, int Cm1) {
    int row = blockIdx.x;   // b*C + cc
    int b = row / C, cc = row % C;
    int tid = threadIdx.x;
    size_t oslab = (size_t)row * M_TOP * 5;
    if (cc == 0) {
        for (int i = tid; i < M_TOP * 5; i += 256) out[oslab + i] = 0.0f;
        return;
    }
    int c = cc - 1;
    __shared__ float lv[M_TOP];
    __shared__ int   lm[M_TOP];
    __shared__ uint32_t nloc;
    if (tid == 0) nloc = 0;
    __syncthreads();
    int cnt = gl_cnt[b];
    for (int i = tid; i < cnt; i += 256) {
        int idx = gl_idx[b * M_TOP + i];
        if (idx / M_TOP == c) {
            uint32_t p = atomicAdd(&nloc, 1u);
            lv[p] = gl_val[b * M_TOP + i];
            lm[p] = idx % M_TOP;
        }
    }
    __syncthreads();
    int nc = (int)nloc;
    if (tid < M_TOP) {
        if (tid < nc) {
            float v = lv[tid]; int m = lm[tid];
            int rk = 0;
            for (int j = 0; j < nc; j++)
                if (lv[j] > v || (lv[j] == v && lm[j] < m)) rk++;
            float4 bb = ((const float4*)cand)[((size_t)(b * Cm1 + c)) * M_TOP + m];
            size_t o = oslab + (size_t)rk * 5;
            out[o] = v; out[o + 1] = bb.x; out[o + 2] = bb.y;
            out[o + 3] = bb.z; out[o + 4] = bb.w;
        } else {
            size_t o = oslab + (size_t)tid * 5;
            out[o] = 0.f; out[o + 1] = 0.f; out[o + 2] = 0.f;
            out[o + 3] = 0.f; out[o + 4] = 0.f;
        }
    }
}

extern "C" void kernel_launch(void* const* d_in, const int* in_sizes, int n_in,
                              void* d_out, int out_size, void* d_ws, size_t ws_size,
                              hipStream_t stream) {
    const float* loc  = (const float*)d_in[0];
    const float* conf = (const float*)d_in[1];
    const float* dbox = (const float*)d_in[2];
    int N   = in_sizes[2] / 4;
    int B   = in_sizes[0] / (4 * N);
    int C   = in_sizes[1] / (B * N);
    int Cm1 = C - 1;
    int M   = Cm1 * M_TOP;                 // 16000 per batch

    char* ws = (char*)d_ws;
    size_t off = 0;
    auto alloc = [&](size_t bytes) -> char* {
        char* p = ws + off;
        off = (off + bytes + 255) & ~(size_t)255;
        return p;
    };
    float* sc     = (float*)alloc((size_t)B * Cm1 * N * sizeof(float));
    float* cand   = (float*)alloc((size_t)B * M * 4 * sizeof(float));
    int*   pcnt   = (int*)alloc((size_t)B * sizeof(int));
    float* cmpval = (float*)alloc((size_t)B * M * sizeof(float));
    int*   cmpidx = (int*)alloc((size_t)B * M * sizeof(int));
    float* gl_val = (float*)alloc((size_t)B * M_TOP * sizeof(float));
    int*   gl_idx = (int*)alloc((size_t)B * M_TOP * sizeof(int));
    int*   gl_cnt = (int*)alloc((size_t)B * sizeof(int));

    int bn = B * N;
    softmax_kernel<<<(bn + 255) / 256, 256, 0, stream>>>(conf, sc, pcnt, B, N, C);
    topk_kernel<<<B * Cm1, TK_BS, 0, stream>>>(sc, loc, dbox, cand, cmpval, cmpidx, pcnt,
                                               B, N, Cm1, M);
    gtop_kernel<<<B, GT_BS, 0, stream>>>(cmpval, cmpidx, pcnt, gl_val, gl_idx, gl_cnt, M);
    out_kernel<<<B * C, 256, 0, stream>>>(gl_val, gl_idx, gl_cnt, cand, (float*)d_out, C, Cm1);
}

// Round 14
// 277.171 us; speedup vs baseline: 1.3384x; 1.0187x over previous
//
#include <hip/hip_runtime.h>
#include <stdint.h>

#define CONF_T 0.01f
#define NMS_T  0.45f
#define M_TOP  200
#define TK_BS  256    // topk block size
#define TCAP   2048   // topk bracket buffer capacity (LDS); overflow -> exact fallback

typedef float float4u __attribute__((ext_vector_type(4), aligned(4)));

__device__ __forceinline__ uint32_t fkey(float f) {
    uint32_t u = __float_as_uint(f);
    return (u & 0x80000000u) ? ~u : (u | 0x80000000u);
}
__device__ __forceinline__ float fkey_inv(uint32_t k) {
    uint32_t u = (k & 0x80000000u) ? (k & 0x7FFFFFFFu) : ~k;
    return __uint_as_float(u);
}

// Parallel suffix-scan bin selection over nb bins (nb multiple of 256).
__device__ __forceinline__ void suffix_select(
        uint32_t* hist, uint32_t* wsum, int nb, uint32_t pref, int shift,
        uint32_t wantv, uint32_t* s_prefix, uint32_t* s_want) {
    int tid = threadIdx.x;
    int lane = tid & 63, w = tid >> 6;
    int bpt = nb >> 8;
    int base = tid * bpt;
    uint32_t loc = 0;
    for (int j = 0; j < bpt; j++) loc += hist[base + j];
    uint32_t sfx = loc;
    #pragma unroll
    for (int d = 1; d < 64; d <<= 1) {
        uint32_t y = __shfl_down(sfx, d);
        if (lane + d < 64) sfx += y;
    }
    if (lane == 0) wsum[w] = sfx;
    __syncthreads();
    uint32_t later = 0;
    for (int j = w + 1; j < TK_BS / 64; j++) later += wsum[j];
    uint32_t run = (sfx - loc) + later;
    for (int j = bpt - 1; j >= 0; j--) {
        uint32_t h = hist[base + j];
        uint32_t s2 = run + h;
        if (run < wantv && s2 >= wantv) {
            *s_prefix = pref | ((uint32_t)(base + j) << shift);
            *s_want   = wantv - run;
        }
        run = s2;
    }
    __syncthreads();
}

__device__ __forceinline__ float4 decode_box(float4 l, float4 d) {
    float cx = d.x + (l.x * 0.1f) * d.z;
    float cy = d.y + (l.y * 0.1f) * d.w;
    float w  = d.z * expf(l.z * 0.2f);
    float h  = d.w * expf(l.w * 0.2f);
    float x1 = cx - w * 0.5f, y1 = cy - h * 0.5f;
    float x2 = x1 + w, y2 = y1 + h;
    float4 o;
    o.x = fminf(fmaxf(x1, 0.f), 1.f);
    o.y = fminf(fmaxf(y1, 0.f), 1.f);
    o.z = fminf(fmaxf(x2, 0.f), 1.f);
    o.w = fminf(fmaxf(y2, 0.f), 1.f);
    return o;
}

// ---------------- Kernel B: softmax + transpose (register-resident) + pcnt init ------
__global__ __launch_bounds__(256, 4) void softmax_kernel(
        const float* __restrict__ conf, float* __restrict__ sc,
        int* __restrict__ pcnt, int B, int N, int C) {
    int r = blockIdx.x * blockDim.x + threadIdx.x;
    if (r < B) pcnt[r] = 0;                 // zero pcnt for the topk dispatch
    if (r >= B * N) return;
    const float* p = conf + (size_t)r * 81;
    float v[81];
    #pragma unroll
    for (int i = 0; i < 20; i++) {
        float4u f = *(const float4u*)(p + 4 * i);
        v[4 * i] = f.x; v[4 * i + 1] = f.y; v[4 * i + 2] = f.z; v[4 * i + 3] = f.w;
    }
    v[80] = p[80];
    float m = v[0];
    #pragma unroll
    for (int c = 1; c < 81; c++) m = fmaxf(m, v[c]);
    float s = 0.f;
    #pragma unroll
    for (int c = 0; c < 81; c++) { float e = expf(v[c] - m); v[c] = e; s += e; }
    int b = r / N, n = r % N;
    float* obase = sc + ((size_t)b * (C - 1)) * N + n;
    #pragma unroll
    for (int c = 1; c < 81; c++) obase[(size_t)(c - 1) * N] = v[c] / s;
}

// ---------------- Kernel C: top-200 + inline decode + fused serial-wave NMS ----------
__global__ __launch_bounds__(TK_BS) void topk_kernel(
        const float* __restrict__ sc, const float* __restrict__ loc,
        const float* __restrict__ dbox,
        float* __restrict__ cand,
        float* __restrict__ cmpval, int* __restrict__ cmpidx,
        int* __restrict__ pcnt,
        int B, int N, int Cm1, int M) {
    const uint32_t KEYN1 = 0x407FFFFFu;        // fkey(-1.0f)
    const uint32_t BIN_N1 = KEYN1 >> 21;       // 0x203
    __shared__ __align__(16) uint32_t hist[2048];
    __shared__ __align__(16) uint32_t tk[TCAP];
    __shared__ int      tix[TCAP];
    __shared__ uint32_t wsum[TK_BS / 64];
    __shared__ uint32_t s_prefix, s_want;
    __shared__ uint32_t ngt, ntie, tcnt;
    __shared__ float    e_val[256];
    __shared__ int      e_idx[256];
    __shared__ int      tiebuf[256];
    __shared__ float    s_sc[M_TOP];
    __shared__ float    s_x1[M_TOP], s_y1[M_TOP], s_x2[M_TOP], s_y2[M_TOP];

    int row = blockIdx.x;                      // b*Cm1 + c
    int b = row / Cm1, c = row % Cm1;
    int tid = threadIdx.x;
    const float* v = sc + (size_t)row * N;
    const float4* v4 = (const float4*)v;
    int n4 = N >> 2;

    // ---- sample phase (2048 strided samples; keys staged in tk[0..2047]) ----
    bool sampled = (N >= 2048) && ((N & 7) == 0);
    uint32_t lo_key = 0xFFFFFFFFu, hi_key = 0xFFFFFFFFu;
    if (sampled) {
        int stride = N >> 3;
        for (int s = 0; s < 8; s++) {
            float f = v[s * stride + tid];
            tk[s * 256 + tid] = fkey(f > CONF_T ? f : -1.0f);
        }
        for (int i = tid; i < 2048; i += TK_BS) hist[i] = 0;
        __syncthreads();
        for (int i = tid; i < 2048; i += TK_BS) atomicAdd(&hist[tk[i] >> 21], 1u);
        __syncthreads();
        suffix_select(hist, wsum, 2048, 0u, 21, 3u, &s_prefix, &s_want);
        uint32_t h = s_prefix >> 21;
        suffix_select(hist, wsum, 2048, 0u, 21, 25u, &s_prefix, &s_want);
        uint32_t l = s_prefix >> 21;
        hi_key = ((h + 1) << 21) - 1u;
        lo_key = (l << 21) - 1u;
        sampled = (l > BIN_N1);
    }

    e_val[tid] = -1.0f; e_idx[tid] = tid;
    if (tid == 0) { ngt = 0; ntie = 0; tcnt = 0; }
    __syncthreads();

    bool ok = false;
    uint32_t G = 0, T = 0;
    if (sampled) {
        // ---- the one full sweep: 8-way unrolled batch loads for MLP ----
        for (int i0 = tid; i0 < n4; i0 += 8 * TK_BS) {
            float4 f[8];
            #pragma unroll
            for (int u = 0; u < 8; u++) {
                int i = i0 + u * TK_BS;
                if (i < n4) f[u] = v4[i];
            }
            #pragma unroll
            for (int u = 0; u < 8; u++) {
                int i = i0 + u * TK_BS;
                if (i < n4) {
                    float mv[4] = { f[u].x > CONF_T ? f[u].x : -1.0f,
                                    f[u].y > CONF_T ? f[u].y : -1.0f,
                                    f[u].z > CONF_T ? f[u].z : -1.0f,
                                    f[u].w > CONF_T ? f[u].w : -1.0f };
                    #pragma unroll
                    for (int j = 0; j < 4; j++) {
                        uint32_t k = fkey(mv[j]);
                        if (k > lo_key) {
                            int idx = 4 * i + j;
                            if (k > hi_key) {
                                uint32_t p = atomicAdd(&ngt, 1u);
                                if (p < 256) { e_val[p] = mv[j]; e_idx[p] = idx; }
                            } else {
                                uint32_t p = atomicAdd(&tcnt, 1u);
                                if (p < TCAP) { tk[p] = k; tix[p] = idx; }
                            }
                        }
                    }
                }
            }
        }
        for (int i = (n4 << 2) + tid; i < N; i += TK_BS) {
            float f = v[i];
            float mv = f > CONF_T ? f : -1.0f;
            uint32_t k = fkey(mv);
            if (k > lo_key) {
                if (k > hi_key) {
                    uint32_t p = atomicAdd(&ngt, 1u);
                    if (p < 256) { e_val[p] = mv; e_idx[p] = i; }
                } else {
                    uint32_t p = atomicAdd(&tcnt, 1u);
                    if (p < TCAP) { tk[p] = k; tix[p] = i; }
                }
            }
        }
        __syncthreads();
        G = ngt; T = tcnt;
        ok = (G <= (uint32_t)M_TOP) && (T <= (uint32_t)TCAP) &&
             (G + T >= (uint32_t)M_TOP);
    }

    uint32_t kth = KEYN1, rfin = 0;
    if (ok) {
        uint32_t want_t = (uint32_t)M_TOP - G;
        if (want_t > 0) {
            for (int i = tid; i < 2048; i += TK_BS) hist[i] = 0;
            __syncthreads();
            for (int i = tid; i < (int)T; i += TK_BS) atomicAdd(&hist[tk[i] >> 21], 1u);
            __syncthreads();
            suffix_select(hist, wsum, 2048, 0u, 21, want_t, &s_prefix, &s_want);
            uint32_t pre0 = s_prefix, w0 = s_want;
            uint32_t bb0 = pre0 >> 21;
            for (int i = tid; i < 2048; i += TK_BS) hist[i] = 0;
            __syncthreads();
            for (int i = tid; i < (int)T; i += TK_BS)
                if ((tk[i] >> 21) == bb0) atomicAdd(&hist[(tk[i] >> 10) & 2047u], 1u);
            __syncthreads();
            suffix_select(hist, wsum, 2048, pre0, 10, w0, &s_prefix, &s_want);
            uint32_t pre1 = s_prefix, w1 = s_want;
            for (int i = tid; i < 1024; i += TK_BS) hist[i] = 0;
            __syncthreads();
            for (int i = tid; i < (int)T; i += TK_BS)
                if ((tk[i] >> 10) == (pre1 >> 10)) atomicAdd(&hist[tk[i] & 1023u], 1u);
            __syncthreads();
            suffix_select(hist, wsum, 1024, pre1, 0, w1, &s_prefix, &s_want);
            kth = s_prefix; rfin = s_want;
            for (int i = tid; i < (int)T; i += TK_BS) {
                uint32_t k = tk[i];
                if (k > kth) {
                    uint32_t p = atomicAdd(&ngt, 1u);
                    if (p < 256) { e_val[p] = fkey_inv(k); e_idx[p] = tix[i]; }
                } else if (k == kth) {
                    uint32_t p = atomicAdd(&ntie, 1u);
                    if (p < 256) tiebuf[p] = tix[i];
                }
            }
            __syncthreads();
        }
    } else {
        // ---- fallback: exact 2-sweep histogram path ----
        e_val[tid] = -1.0f; e_idx[tid] = tid;
        if (tid == 0) { ngt = 0; ntie = 0; tcnt = 0; }
        for (int i = tid; i < 2048; i += TK_BS) hist[i] = 0;
        __syncthreads();
        for (int i = tid; i < n4; i += TK_BS) {
            float4 f = v4[i];
            atomicAdd(&hist[fkey(f.x > CONF_T ? f.x : -1.0f) >> 21], 1u);
            atomicAdd(&hist[fkey(f.y > CONF_T ? f.y : -1.0f) >> 21], 1u);
            atomicAdd(&hist[fkey(f.z > CONF_T ? f.z : -1.0f) >> 21], 1u);
            atomicAdd(&hist[fkey(f.w > CONF_T ? f.w : -1.0f) >> 21], 1u);
        }
        for (int i = (n4 << 2) + tid; i < N; i += TK_BS)
            atomicAdd(&hist[fkey(v[i] > CONF_T ? v[i] : -1.0f) >> 21], 1u);
        __syncthreads();
        suffix_select(hist, wsum, 2048, 0u, 21, M_TOP, &s_prefix, &s_want);
        uint32_t b0 = s_prefix >> 21;
        uint32_t want1 = s_want;
        bool collect_ties = (b0 != BIN_N1);
        for (int i = tid; i < N; i += TK_BS) {
            float f = v[i];
            float mv = f > CONF_T ? f : -1.0f;
            uint32_t k = fkey(mv);
            uint32_t bin = k >> 21;
            if (bin > b0) {
                uint32_t p = atomicAdd(&ngt, 1u);
                if (p < 256) { e_val[p] = mv; e_idx[p] = i; }
            } else if (bin == b0 && collect_ties) {
                uint32_t p = atomicAdd(&tcnt, 1u);
                if (p < TCAP) { tk[p] = k; tix[p] = i; }
            }
        }
        __syncthreads();
        if (collect_ties && tcnt <= TCAP) {
            int Tl = (int)tcnt;
            for (int i = tid; i < 2048; i += TK_BS) hist[i] = 0;
            __syncthreads();
            for (int i = tid; i < Tl; i += TK_BS) atomicAdd(&hist[(tk[i] >> 10) & 2047u], 1u);
            __syncthreads();
            suffix_select(hist, wsum, 2048, b0 << 21, 10, want1, &s_prefix, &s_want);
            uint32_t pre2 = s_prefix; uint32_t want2 = s_want;
            uint32_t b1 = (pre2 >> 10) & 2047u;
            for (int i = tid; i < 1024; i += TK_BS) hist[i] = 0;
            __syncthreads();
            for (int i = tid; i < Tl; i += TK_BS)
                if (((tk[i] >> 10) & 2047u) == b1) atomicAdd(&hist[tk[i] & 1023u], 1u);
            __syncthreads();
            suffix_select(hist, wsum, 1024, pre2, 0, want2, &s_prefix, &s_want);
            kth = s_prefix; rfin = s_want;
            for (int i = tid; i < Tl; i += TK_BS) {
                uint32_t k = tk[i];
                if (k > kth) {
                    uint32_t p = atomicAdd(&ngt, 1u);
                    if (p < 256) { e_val[p] = fkey_inv(k); e_idx[p] = tix[i]; }
                } else if (k == kth) {
                    uint32_t p = atomicAdd(&ntie, 1u);
                    if (p < 256) tiebuf[p] = tix[i];
                }
            }
            __syncthreads();
        } else if (collect_ties) {
            const int shifts[2] = {10, 0};
            const int nbins_[2] = {2048, 1024};
            if (tid == 0) { s_prefix = b0 << 21; s_want = want1; }
            __syncthreads();
            for (int lev = 0; lev < 2; lev++) {
                int shift = shifts[lev];
                int nb = nbins_[lev];
                uint32_t bmask = (uint32_t)nb - 1u;
                uint32_t pref = s_prefix, wantv = s_want;
                uint32_t pmask = 0xFFFFFFFFu << (shift + ((nb == 2048) ? 11 : 10));
                for (int i = tid; i < nb; i += TK_BS) hist[i] = 0;
                __syncthreads();
                for (int i = tid; i < N; i += TK_BS) {
                    float f = v[i];
                    uint32_t k = fkey(f > CONF_T ? f : -1.0f);
                    if ((k & pmask) == (pref & pmask)) atomicAdd(&hist[(k >> shift) & bmask], 1u);
                }
                __syncthreads();
                suffix_select(hist, wsum, nb, pref, shift, wantv, &s_prefix, &s_want);
            }
            kth = s_prefix; rfin = s_want;
            for (int i = tid; i < N; i += TK_BS) {
                float f = v[i];
                float mv = f > CONF_T ? f : -1.0f;
                uint32_t k = fkey(mv);
                if ((k >> 21) == b0) {
                    if (k > kth) {
                        uint32_t p = atomicAdd(&ngt, 1u);
                        if (p < 256) { e_val[p] = mv; e_idx[p] = i; }
                    } else if (k == kth) {
                        uint32_t p = atomicAdd(&ntie, 1u);
                        if (p < 256) tiebuf[p] = i;
                    }
                }
            }
            __syncthreads();
        }
    }

    // ---- ties, rank order, inline box decode -> LDS + cand ----
    uint32_t gcount = min(ngt, (uint32_t)M_TOP);
    uint32_t nt = min(ntie, 256u);
    if (tid < (int)nt) {
        int mine = tiebuf[tid];
        uint32_t rk = 0;
        for (uint32_t j = 0; j < nt; j++) if (tiebuf[j] < mine) rk++;
        if (rk < rfin) {
            uint32_t slot = gcount + rk;
            if (slot < M_TOP) { e_val[slot] = fkey_inv(kth); e_idx[slot] = mine; }
        }
    }
    __syncthreads();
    if (tid < M_TOP) {
        float mv = e_val[tid]; int mi = e_idx[tid];
        uint32_t mk = fkey(mv);
        uint32_t rk = 0;
        for (int j = 0; j < M_TOP; j++) {
            uint32_t jk = fkey(e_val[j]); int ji = e_idx[j];
            if (jk > mk || (jk == mk && ji < mi)) rk++;
        }
        float4 l = ((const float4*)loc)[(size_t)b * N + mi];
        float4 d = ((const float4*)dbox)[mi];
        float4 bx = decode_box(l, d);
        ((float4*)cand)[(size_t)row * M_TOP + rk] = bx;   // for out_kernel gather
        s_sc[rk] = mv;
        s_x1[rk] = bx.x; s_y1[rk] = bx.y; s_x2[rk] = bx.z; s_y2[rk] = bx.w;
    }
    __syncthreads();

    // ---- fused greedy NMS + compaction on wave 0 (serial-wave form) ----
    if (tid < 64) {
        int lane = tid;
        float x1[4], y1[4], x2[4], y2[4], ar[4], sv[4];
        int act[4], kf[4];
        #pragma unroll
        for (int s = 0; s < 4; s++) {
            int j = s * 64 + lane;
            if (j < M_TOP) {
                x1[s] = s_x1[j]; y1[s] = s_y1[j]; x2[s] = s_x2[j]; y2[s] = s_y2[j];
                ar[s] = (x2[s] - x1[s]) * (y2[s] - y1[s]);
                sv[s] = s_sc[j];
            } else { x1[s]=0.f; y1[s]=0.f; x2[s]=0.f; y2[s]=0.f; ar[s]=0.f; sv[s]=-1.0f; }
            act[s] = (sv[s] > CONF_T) ? 1 : 0;
            kf[s] = 0;
        }
        #pragma unroll
        for (int si = 0; si < 4; si++) {
            int lim = M_TOP - si * 64; if (lim > 64) lim = 64;
            for (int li = 0; li < lim; li++) {
                int a = __shfl(act[si], li);
                if (a) {
                    if (lane == li) kf[si] = 1;
                    float bx1 = __shfl(x1[si], li);
                    float by1 = __shfl(y1[si], li);
                    float bx2 = __shfl(x2[si], li);
                    float by2 = __shfl(y2[si], li);
                    float bar = __shfl(ar[si], li);
                    #pragma unroll
                    for (int s = 0; s < 4; s++) {
                        float xx1 = fmaxf(bx1, x1[s]);
                        float yy1 = fmaxf(by1, y1[s]);
                        float xx2 = fminf(bx2, x2[s]);
                        float yy2 = fminf(by2, y2[s]);
                        float inter = fmaxf(xx2 - xx1, 0.f) * fmaxf(yy2 - yy1, 0.f);
                        float uni = (ar[s] - inter) + bar;
                        float iou = inter / uni;
                        if (!(iou <= NMS_T)) act[s] = 0;   // NaN suppresses
                    }
                }
            }
        }
        unsigned long long ball[4];
        int total = 0;
        #pragma unroll
        for (int s = 0; s < 4; s++) { ball[s] = __ballot(kf[s] != 0); total += (int)__popcll(ball[s]); }
        int base = 0;
        if (lane == 0 && total > 0) base = atomicAdd(&pcnt[b], total);
        base = __shfl(base, 0);
        unsigned long long lower = (lane == 0) ? 0ull : (~0ull >> (64 - lane));
        int off = base;
        #pragma unroll
        for (int s = 0; s < 4; s++) {
            if (kf[s]) {
                int pos = off + (int)__popcll(ball[s] & lower);
                cmpval[(size_t)b * M + pos] = sv[s];
                cmpidx[(size_t)b * M + pos] = c * M_TOP + s * 64 + lane;
            }
            off += (int)__popcll(ball[s]);
        }
    }
}

// ---------------- Kernel E: top-200 of positives -> compact (val,idx) list ----------
#define GT_BS 1024
__global__ __launch_bounds__(GT_BS) void gtop_kernel(
        const float* __restrict__ cmpval, const int* __restrict__ cmpidx,
        const int* __restrict__ pcnt, float* __restrict__ gl_val,
        int* __restrict__ gl_idx, int* __restrict__ gl_cnt, int M) {
    int b = blockIdx.x;
    int tid = threadIdx.x;
    int P = pcnt[b];
    const float* cv = cmpval + (size_t)b * M;
    const int*   ci = cmpidx + (size_t)b * M;
    if (P <= M_TOP) {
        for (int i = tid; i < P; i += GT_BS) {
            gl_val[b * M_TOP + i] = cv[i];
            gl_idx[b * M_TOP + i] = ci[i];
        }
        if (tid == 0) gl_cnt[b] = P;
        return;
    }
    __shared__ uint32_t hist[256];
    __shared__ uint32_t s_prefix, s_want;
    __shared__ int tiebuf[256];
    __shared__ uint32_t ntie, wcnt;
    __shared__ int cutoff;
    if (tid == 0) { s_prefix = 0; s_want = M_TOP; }
    for (int pass = 0; pass < 4; pass++) {
        if (tid < 256) hist[tid] = 0;
        __syncthreads();
        uint32_t prefix = s_prefix;
        int shift = 24 - 8 * pass;
        for (int i = tid; i < P; i += GT_BS) {
            uint32_t k = fkey(cv[i]);
            bool ok = (pass == 0) || ((k >> (shift + 8)) == (prefix >> (shift + 8)));
            if (ok) atomicAdd(&hist[(k >> shift) & 255u], 1u);
        }
        __syncthreads();
        if (tid == 0) {
            uint32_t want = s_want, cum = 0; int bin = 0;
            for (int bb = 255; bb >= 0; bb--) {
                if (cum + hist[bb] >= want) { bin = bb; break; }
                cum += hist[bb];
            }
            s_want = want - cum;
            s_prefix = prefix | ((uint32_t)bin << shift);
        }
        __syncthreads();
    }
    uint32_t kth = s_prefix, rfin = s_want;
    if (tid == 0) { ntie = 0; cutoff = -1; wcnt = 0; }
    __syncthreads();
    for (int i = tid; i < P; i += GT_BS) {
        if (fkey(cv[i]) == kth) { uint32_t p = atomicAdd(&ntie, 1u); if (p < 256) tiebuf[p] = ci[i]; }
    }
    __syncthreads();
    uint32_t nt = min(ntie, 256u);
    if (tid < (int)nt) {
        int mine = tiebuf[tid];
        uint32_t rk = 0;
        for (uint32_t j = 0; j < nt; j++) if (tiebuf[j] < mine) rk++;
        if (rk == rfin - 1) cutoff = mine;
    }
    __syncthreads();
    int cut = cutoff;
    for (int i = tid; i < P; i += GT_BS) {
        uint32_t k = fkey(cv[i]);
        if (k > kth || (k == kth && ci[i] <= cut)) {
            uint32_t p = atomicAdd(&wcnt, 1u);
            gl_val[b * M_TOP + p] = cv[i];
            gl_idx[b * M_TOP + p] = ci[i];
        }
    }
    if (tid == 0) gl_cnt[b] = M_TOP;
}

// ---------------- Kernel F: per-class sort + FULL output write (no memset) ----------
__global__ __launch_bounds__(256) void out_kernel(
        const float* __restrict__ gl_val, const int* __restrict__ gl_idx,
        const int* __restrict__ gl_cnt, const float* __restrict__ cand,
        float* __restrict__ out, int C, int Cm1) {
    int row = blockIdx.x;   // b*C + cc
    int b = row / C, cc = row % C;
    int tid = threadIdx.x;
    size_t oslab = (size_t)row * M_TOP * 5;
    if (cc == 0) {
        for (int i = tid; i < M_TOP * 5; i += 256) out[oslab + i] = 0.0f;
        return;
    }
    int c = cc - 1;
    __shared__ float lv[M_TOP];
    __shared__ int   lm[M_TOP];
    __shared__ uint32_t nloc;
    if (tid == 0) nloc = 0;
    __syncthreads();
    int cnt = gl_cnt[b];
    for (int i = tid; i < cnt; i += 256) {
        int idx = gl_idx[b * M_TOP + i];
        if (idx / M_TOP == c) {
            uint32_t p = atomicAdd(&nloc, 1u);
            lv[p] = gl_val[b * M_TOP + i];
            lm[p] = idx % M_TOP;
        }
    }
    __syncthreads();
    int nc = (int)nloc;
    if (tid < M_TOP) {
        if (tid < nc) {
            float v = lv[tid]; int m = lm[tid];
            int rk = 0;
            for (int j = 0; j < nc; j++)
                if (lv[j] > v || (lv[j] == v && lm[j] < m)) rk++;
            float4 bb = ((const float4*)cand)[((size_t)(b * Cm1 + c)) * M_TOP + m];
            size_t o = oslab + (size_t)rk * 5;
            out[o] = v; out[o + 1] = bb.x; out[o + 2] = bb.y;
            out[o + 3] = bb.z; out[o + 4] = bb.w;
        } else {
            size_t o = oslab + (size_t)tid * 5;
            out[o] = 0.f; out[o + 1] = 0.f; out[o + 2] = 0.f;
            out[o + 3] = 0.f; out[o + 4] = 0.f;
        }
    }
}

extern "C" void kernel_launch(void* const* d_in, const int* in_sizes, int n_in,
                              void* d_out, int out_size, void* d_ws, size_t ws_size,
                              hipStream_t stream) {
    const float* loc  = (const float*)d_in[0];
    const float* conf = (const float*)d_in[1];
    const float* dbox = (const float*)d_in[2];
    int N   = in_sizes[2] / 4;
    int B   = in_sizes[0] / (4 * N);
    int C   = in_sizes[1] / (B * N);
    int Cm1 = C - 1;
    int M   = Cm1 * M_TOP;                 // 16000 per batch

    char* ws = (char*)d_ws;
    size_t off = 0;
    auto alloc = [&](size_t bytes) -> char* {
        char* p = ws + off;
        off = (off + bytes + 255) & ~(size_t)255;
        return p;
    };
    float* sc     = (float*)alloc((size_t)B * Cm1 * N * sizeof(float));
    float* cand   = (float*)alloc((size_t)B * M * 4 * sizeof(float));
    int*   pcnt   = (int*)alloc((size_t)B * sizeof(int));
    float* cmpval = (float*)alloc((size_t)B * M * sizeof(float));
    int*   cmpidx = (int*)alloc((size_t)B * M * sizeof(int));
    float* gl_val = (float*)alloc((size_t)B * M_TOP * sizeof(float));
    int*   gl_idx = (int*)alloc((size_t)B * M_TOP * sizeof(int));
    int*   gl_cnt = (int*)alloc((size_t)B * sizeof(int));

    int bn = B * N;
    softmax_kernel<<<(bn + 255) / 256, 256, 0, stream>>>(conf, sc, pcnt, B, N, C);
    topk_kernel<<<B * Cm1, TK_BS, 0, stream>>>(sc, loc, dbox, cand, cmpval, cmpidx, pcnt,
                                               B, N, Cm1, M);
    gtop_kernel<<<B, GT_BS, 0, stream>>>(cmpval, cmpidx, pcnt, gl_val, gl_idx, gl_cnt, M);
    out_kernel<<<B * C, 256, 0, stream>>>(gl_val, gl_idx, gl_cnt, cand, (float*)d_out, C, Cm1);
}